// Round 5
// baseline (3888.319 us; speedup 1.0000x reference)
//
#include <hip/hip_runtime.h>
#include <math.h>

#define Bz 32
#define Tz 512
#define Ez 256
#define Hz 512
#define FCH 446   // 180 conv + 10 rev + 256 x

__device__ __forceinline__ float sigf(float x){ return 1.0f/(1.0f + __expf(-x)); }
__device__ __forceinline__ float tanhfast(float x){ return 1.0f - 2.0f/(__expf(2.0f*x) + 1.0f); }

// ---------------- conv (3 kernels, SAME pad) + rxw = x_rev @ rev_Wx + x-copy into feat ----
__global__ __launch_bounds__(256) void k_conv(
    const float* __restrict__ x,
    const float* __restrict__ w1, const float* __restrict__ b1,
    const float* __restrict__ w2, const float* __restrict__ b2,
    const float* __restrict__ w3, const float* __restrict__ b3,
    const float* __restrict__ rwx,
    float* __restrict__ feat, float* __restrict__ rxw)
{
  __shared__ __align__(16) float xs[256*40];   // xs[e*40 + i] = x[b][t0-2+i], i in 0..35
  int b  = blockIdx.x >> 4;
  int t0 = (blockIdx.x & 15) * 32;
  int tid = threadIdx.x;
  for (int i = 0; i < 36; ++i){
    int t = t0 - 2 + i;
    xs[tid*40 + i] = (t >= 0 && t < Tz) ? x[(b*Tz + t)*Ez + tid] : 0.0f;
  }
  __syncthreads();
  // x-part of d0 input: feat[t][b][190+e] = x[b][t][e]
  for (int i = 0; i < 32; ++i){
    int t = t0 + i;
    feat[((size_t)t*Bz + b)*FCH + 190 + tid] = xs[tid*40 + i + 2];
  }
  int tq = tid & 7, cs = tid >> 3;             // 8 t-quads x 32 c-slots
  float acc[6][4];
  float racc[2][4];
  #pragma unroll
  for (int ci = 0; ci < 6; ++ci){
    int c = cs + 32*ci;
    float bv = 0.0f;
    if (c < 60) bv = b1[c];
    else if (c < 120) bv = b2[c-60];
    else if (c < 180) bv = b3[c-120];
    acc[ci][0]=acc[ci][1]=acc[ci][2]=acc[ci][3]=bv;
  }
  #pragma unroll
  for (int ji = 0; ji < 2; ++ji){ racc[ji][0]=racc[ji][1]=racc[ji][2]=racc[ji][3]=0.0f; }

  for (int e = 0; e < 256; ++e){
    const float* xr = &xs[e*40 + 4*tq];
    float4 wa = *(const float4*)(xr);
    float4 wb = *(const float4*)(xr + 4);
    float wd[8] = {wa.x, wa.y, wa.z, wa.w, wb.x, wb.y, wb.z, wb.w};
    #pragma unroll
    for (int ci = 0; ci < 6; ++ci){
      int c = cs + 32*ci;
      if (c < 60){
        #pragma unroll
        for (int k = 0; k < 3; ++k){
          float wv = w1[(k*256 + e)*60 + c];
          #pragma unroll
          for (int j = 0; j < 4; ++j) acc[ci][j] = fmaf(wd[1 + j + k], wv, acc[ci][j]);
        }
      } else if (c < 120){
        int cc = c - 60;
        #pragma unroll
        for (int k = 0; k < 4; ++k){
          float wv = w2[(k*256 + e)*60 + cc];
          #pragma unroll
          for (int j = 0; j < 4; ++j) acc[ci][j] = fmaf(wd[1 + j + k], wv, acc[ci][j]);
        }
      } else if (c < 180){
        int cc = c - 120;
        #pragma unroll
        for (int k = 0; k < 5; ++k){
          float wv = w3[(k*256 + e)*60 + cc];
          #pragma unroll
          for (int j = 0; j < 4; ++j) acc[ci][j] = fmaf(wd[j + k], wv, acc[ci][j]);
        }
      }
    }
    #pragma unroll
    for (int ji = 0; ji < 2; ++ji){
      int jc = cs + 32*ji;
      if (jc < 40){
        float wv = rwx[e*40 + jc];
        #pragma unroll
        for (int j = 0; j < 4; ++j) racc[ji][j] = fmaf(wd[2 + j], wv, racc[ji][j]);
      }
    }
  }
  #pragma unroll
  for (int ci = 0; ci < 6; ++ci){
    int c = cs + 32*ci;
    if (c < 180){
      #pragma unroll
      for (int j = 0; j < 4; ++j){
        int t = t0 + 4*tq + j;
        if (t >= 1) feat[((size_t)(t-1)*Bz + b)*FCH + c] = acc[ci][j];
      }
    }
  }
  #pragma unroll
  for (int ji = 0; ji < 2; ++ji){
    int jc = cs + 32*ji;
    if (jc < 40){
      #pragma unroll
      for (int j = 0; j < 4; ++j){
        int t = t0 + 4*tq + j;
        rxw[((size_t)(511 - t)*Bz + b)*40 + jc] = racc[ji][j];
      }
    }
  }
}

// ---------------- reverse LSTM (hidden 10), one wave per batch row ----------------
__global__ __launch_bounds__(64) void k_rev(const float* __restrict__ rxw,
    const float* __restrict__ revWh, const float* __restrict__ revb, float* __restrict__ feat){
  int b = blockIdx.x;
  int j = threadIdx.x;
  float wreg[10];
  float bias = 0.0f;
  #pragma unroll
  for (int k = 0; k < 10; ++k) wreg[k] = 0.0f;
  if (j < 40){
    bias = revb[j];
    #pragma unroll
    for (int k = 0; k < 10; ++k) wreg[k] = revWh[k*40 + j];
  }
  float h[10];
  #pragma unroll
  for (int k = 0; k < 10; ++k) h[k] = 0.0f;
  float c = 0.0f;
  for (int s = 0; s < Tz; ++s){
    float z = bias + ((j < 40) ? rxw[(s*Bz + b)*40 + j] : 0.0f);
    #pragma unroll
    for (int k = 0; k < 10; ++k) z = fmaf(h[k], wreg[k], z);
    float a = (j >= 20 && j < 30) ? tanhfast(z) : sigf(z);
    float af = __shfl(a, j + 10);
    float ag = __shfl(a, j + 20);
    float ao = __shfl(a, j + 30);
    if (j < 10) c = af*c + a*ag;
    float hn = ao * tanhfast(c);
    #pragma unroll
    for (int k = 0; k < 10; ++k) h[k] = __shfl(hn, k);
    if (j < 10 && s >= 1) feat[((size_t)(s-1)*Bz + b)*FCH + 180 + j] = hn;
  }
}

// ---------------- hid = relu(feat @ d0_W + d0_b): 32 rows x 100 cols per block ----------------
__global__ __launch_bounds__(256) void k_hid(const float* __restrict__ feat,
    const float* __restrict__ d0W, const float* __restrict__ d0b, float* __restrict__ hid){
  __shared__ __align__(16) float fT[446*36];   // fT[ch*36 + r]
  int r0 = blockIdx.x * 32;
  int tid = threadIdx.x;
  for (int r = 0; r < 32; ++r){
    fT[tid*36 + r] = feat[(size_t)(r0 + r)*FCH + tid];
    if (tid < 190) fT[(tid + 256)*36 + r] = feat[(size_t)(r0 + r)*FCH + tid + 256];
  }
  __syncthreads();
  int cs = tid & 31, rq = tid >> 5;            // 32 c-slots (4 cols each), 8 row-quads
  if (cs < 25){
    float4 accv[4];
    #pragma unroll
    for (int jc = 0; jc < 4; ++jc) accv[jc] = make_float4(0.f,0.f,0.f,0.f);
    for (int k = 0; k < 446; ++k){
      float4 xv = *(const float4*)&fT[k*36 + 4*rq];
      float4 wv = *(const float4*)&d0W[k*100 + 4*cs];
      accv[0].x = fmaf(xv.x, wv.x, accv[0].x); accv[0].y = fmaf(xv.y, wv.x, accv[0].y);
      accv[0].z = fmaf(xv.z, wv.x, accv[0].z); accv[0].w = fmaf(xv.w, wv.x, accv[0].w);
      accv[1].x = fmaf(xv.x, wv.y, accv[1].x); accv[1].y = fmaf(xv.y, wv.y, accv[1].y);
      accv[1].z = fmaf(xv.z, wv.y, accv[1].z); accv[1].w = fmaf(xv.w, wv.y, accv[1].w);
      accv[2].x = fmaf(xv.x, wv.z, accv[2].x); accv[2].y = fmaf(xv.y, wv.z, accv[2].y);
      accv[2].z = fmaf(xv.z, wv.z, accv[2].z); accv[2].w = fmaf(xv.w, wv.z, accv[2].w);
      accv[3].x = fmaf(xv.x, wv.w, accv[3].x); accv[3].y = fmaf(xv.y, wv.w, accv[3].y);
      accv[3].z = fmaf(xv.z, wv.w, accv[3].z); accv[3].w = fmaf(xv.w, wv.w, accv[3].w);
    }
    #pragma unroll
    for (int i = 0; i < 4; ++i){
      int row = r0 + 4*rq + i;
      float4 o;
      float vi[4] = { i==0?accv[0].x:(i==1?accv[0].y:(i==2?accv[0].z:accv[0].w)),
                      i==0?accv[1].x:(i==1?accv[1].y:(i==2?accv[1].z:accv[1].w)),
                      i==0?accv[2].x:(i==1?accv[2].y:(i==2?accv[2].z:accv[2].w)),
                      i==0?accv[3].x:(i==1?accv[3].y:(i==2?accv[3].z:accv[3].w)) };
      o.x = fmaxf(vi[0] + d0b[4*cs+0], 0.0f);
      o.y = fmaxf(vi[1] + d0b[4*cs+1], 0.0f);
      o.z = fmaxf(vi[2] + d0b[4*cs+2], 0.0f);
      o.w = fmaxf(vi[3] + d0b[4*cs+3], 0.0f);
      *(float4*)&hid[(size_t)row*100 + 4*cs] = o;
    }
  }
}

// ---------------- pi + gumbel softmax -> d0,d1 (64 rows per block) ----------------
__global__ __launch_bounds__(128) void k_pi(const float* __restrict__ hid,
    const float* __restrict__ d1W, const float* __restrict__ d1b,
    const float* __restrict__ gum, float* __restrict__ d0a, float* __restrict__ d1a){
  __shared__ float hidL[64*100];
  int r0 = blockIdx.x * 64;
  int tid = threadIdx.x;
  for (int i = 0; i < 50; ++i) hidL[tid + 128*i] = hid[(size_t)r0*100 + tid + 128*i];
  __syncthreads();
  int r = tid >> 1, pp = tid & 1;
  float s = d1b[pp];
  for (int m = 0; m < 100; ++m) s = fmaf(hidL[r*100 + m], d1W[m*2 + pp], s);
  int row = r0 + r;
  float a = (s + gum[row*2 + pp]) / 1e-5f;
  float other = __shfl_xor(a, 1);
  float mx = fmaxf(a, other);
  float ea = expf(a - mx), eb = expf(other - mx);
  float d = ea / (ea + eb);
  if (pp == 0) d0a[row] = d; else d1a[row] = d;
}

// ---------------- xzG[((g*T + t)*2048 + col)*4 + b'] = x[b][t] @ cell_Wx + cell_b ----------
__global__ __launch_bounds__(256) void k_xz(const float* __restrict__ x,
    const float* __restrict__ Wx, const float* __restrict__ cb, float* __restrict__ xzG){
  __shared__ __align__(16) float xT[256*36];   // xT[e*36 + b]
  int t  = blockIdx.x & 511;
  int c0 = (blockIdx.x >> 9) * 128;
  int tid = threadIdx.x;
  for (int b = 0; b < 32; ++b){
    xT[tid*36 + b] = x[(b*Tz + t)*Ez + tid];
  }
  __syncthreads();
  int cs = tid & 31, rq = tid >> 5;            // 32 col-slots (4 cols), 8 batch-quads (=groups)
  float4 accv[4];
  #pragma unroll
  for (int jc = 0; jc < 4; ++jc) accv[jc] = make_float4(0.f,0.f,0.f,0.f);
  float4 wv = *(const float4*)&Wx[c0 + 4*cs];  // e = 0 prefetch
  for (int e = 0; e < 256; ++e){
    float4 wc = wv;
    if (e != 255) wv = *(const float4*)&Wx[(e+1)*2048 + c0 + 4*cs];
    float4 xv = *(const float4*)&xT[e*36 + 4*rq];
    accv[0].x = fmaf(xv.x, wc.x, accv[0].x); accv[0].y = fmaf(xv.y, wc.x, accv[0].y);
    accv[0].z = fmaf(xv.z, wc.x, accv[0].z); accv[0].w = fmaf(xv.w, wc.x, accv[0].w);
    accv[1].x = fmaf(xv.x, wc.y, accv[1].x); accv[1].y = fmaf(xv.y, wc.y, accv[1].y);
    accv[1].z = fmaf(xv.z, wc.y, accv[1].z); accv[1].w = fmaf(xv.w, wc.y, accv[1].w);
    accv[2].x = fmaf(xv.x, wc.z, accv[2].x); accv[2].y = fmaf(xv.y, wc.z, accv[2].y);
    accv[2].z = fmaf(xv.z, wc.z, accv[2].z); accv[2].w = fmaf(xv.w, wc.z, accv[2].w);
    accv[3].x = fmaf(xv.x, wc.w, accv[3].x); accv[3].y = fmaf(xv.y, wc.w, accv[3].y);
    accv[3].z = fmaf(xv.z, wc.w, accv[3].z); accv[3].w = fmaf(xv.w, wc.w, accv[3].w);
  }
  #pragma unroll
  for (int jc = 0; jc < 4; ++jc){
    int col = c0 + 4*cs + jc;
    float bv = cb[col];
    float4 o = accv[jc];
    o.x += bv; o.y += bv; o.z += bv; o.w += bv;
    *(float4*)&xzG[(((size_t)rq*Tz + t)*2048 + col)*4] = o;
  }
}

// ---------------- persistent scan kernel v9: 2-barrier step, register h/c, wave0 tail ----
// 256 blocks x 512 threads (1 block/CU). Reverted to the xzG-based round-0 structure
// (in-scan x@Wx fusion measured: +342us in-scan vs +307us saved outside — a wash with
// worse counters; k_xz restored).
// Critical-path change vs round 0 (4 barriers -> 2):
//  * hold is this thread's own previous hnew -> kept in h_reg; kills the hL hold-read
//    and the gates->staging LDS hazard.
//  * reduce + gates merged into wave 0: reads 32 partials straight from part[]
//    (64 consecutive floats per (kg,gate) read -> conflict-free), adds the xz values it
//    prefetched at step start (bias already folded in k_xz), computes gates, publishes
//    hnew, drains with a wave-local s_waitcnt vmcnt(0), stores the tag, then stores out.
//    SYNC3 + SYNC4 are gone; waves 1-7 fall through SYNC2 directly into next-step
//    polling while wave 0 finishes the tail -> the gate tail overlaps the inter-block
//    propagation window instead of gating it.
// Safety: publish still happens after SYNC2 (part complete) and staging still precedes
// SYNC1, so the all-to-all back-pressure argument from round 0 is unchanged.
__global__ __launch_bounds__(512, 2) void k_scan(
    const float* __restrict__ Wh, const float* __restrict__ xzG,
    const float* __restrict__ d0a, const float* __restrict__ d1a,
    float* __restrict__ hG,              // [8 groups][2 bufs][4*512]
    unsigned int* __restrict__ tags,     // [8][32]
    float* __restrict__ out)
{
  __shared__ __align__(16) float hL[4*520];    // swizzled h, row stride 520
  __shared__ __align__(16) float part[8*260];  // 8 kgroups x 64 cols x 4 b, stride 260
  __shared__ float dv0L[2048];                 // [t*4 + bb], staged once
  __shared__ float dv1L[2048];

  int tid = threadIdx.x;
  int g = blockIdx.x & 7;
  int m = blockIdx.x >> 3;
  int w = tid >> 6;                      // wave 0..7
  int lane = tid & 63;                   // = kseg

  // one-time: weights into VGPRs straight from Wh[k][col]:
  // wreg[ci][j] = Wh[(lane*8+j)*2048 + colbase + ci], cols contiguous per wave.
  float wreg[8][8];
  {
    int colbase = ((w >> 1) << 9) + (m << 4) + ((w & 1) << 3);
    #pragma unroll
    for (int j = 0; j < 8; ++j){
      const float4* wp = (const float4*)(Wh + (size_t)(lane*8 + j)*2048 + colbase);
      float4 a = wp[0], bq = wp[1];
      wreg[0][j]=a.x;  wreg[1][j]=a.y;  wreg[2][j]=a.z;  wreg[3][j]=a.w;
      wreg[4][j]=bq.x; wreg[5][j]=bq.y; wreg[6][j]=bq.z; wreg[7][j]=bq.w;
    }
  }
  // one-time: gate coefficients to LDS
  for (int i = tid; i < 2048; i += 512){
    int tt = i >> 2, bb = i & 3;
    dv0L[i] = d0a[tt*32 + (g << 2) + bb];
    dv1L[i] = d1a[tt*32 + (g << 2) + bb];
  }

  // swizzled LDS addresses for this lane's two h quads (k = lane*8 .. +8)
  int q0 = 2*lane;
  int sw = (q0 >> 3) & 3;
  int p0 = ((q0  ) ^ sw) << 2;
  int p1 = ((q0+1) ^ sw) << 2;

  // staging role: thread stages quad (b = tid>>7, q = tid&127); producer = q>>2
  int stb = tid >> 7, stq = tid & 127;
  int stp = (stq ^ ((stq >> 3) & 3)) << 2;
  const int hrow = 520;
  const unsigned int* mytag = tags + (g << 5) + (stq >> 2);

  // wave0 gate/reduce role (tid<64): jl = tid>>2 (h col in m-slice), bb = tid&3
  // xz addr for gate gi: xzG[(g*T+t)*8192 + (gi*512 + m*16 + jl)*4 + bb]
  //                      = (g*T+t)*8192 + (m*16+jl)*4 + bb + gi*8192... no: gi*512*4=gi*2048
  size_t xzb = (size_t)((m << 4) + (tid >> 2))*4 + (tid & 3);   // + (g*T+t)*8192 + gi*2048

  float* hg0 = hG + (size_t)(g*2 + 0) * (4*512);
  float* hg1 = hG + (size_t)(g*2 + 1) * (4*512);

  float c_reg = 0.0f;                    // cell state (tid<64)
  float h_reg = 0.0f;                    // own h state (tid<64) — hold == prev hnew

  __syncthreads();                       // dv staged

  for (int t = 0; t < Tz; ++t){
    const float* hcur = (t & 1) ? hg1 : hg0;
    float*       hnxt = (t & 1) ? hg0 : hg1;

    // ---- wave0: issue xz loads for this step early (hidden under staging+matvec) ----
    float xz4[4] = {0.f, 0.f, 0.f, 0.f};
    if (tid < 64){
      size_t base = ((size_t)(g*Tz + t))*8192 + xzb;
      #pragma unroll
      for (int gi = 0; gi < 4; ++gi)
        xz4[gi] = xzG[base + (size_t)gi*2048];
    }

    // ---- stage group h (gen t): poll own producer's tag, then load its quad ----
    if (t == 0){
      *(float4*)&hL[stb*hrow + stp] = make_float4(0.f,0.f,0.f,0.f);
    } else {
      while (__hip_atomic_load(mytag, __ATOMIC_RELAXED, __HIP_MEMORY_SCOPE_AGENT)
             < (unsigned)t) { }
      const float* src = hcur + stb*512 + stq*4;
      float4 v;
      v.x = __hip_atomic_load(src+0, __ATOMIC_RELAXED, __HIP_MEMORY_SCOPE_AGENT);
      v.y = __hip_atomic_load(src+1, __ATOMIC_RELAXED, __HIP_MEMORY_SCOPE_AGENT);
      v.z = __hip_atomic_load(src+2, __ATOMIC_RELAXED, __HIP_MEMORY_SCOPE_AGENT);
      v.w = __hip_atomic_load(src+3, __ATOMIC_RELAXED, __HIP_MEMORY_SCOPE_AGENT);
      *(float4*)&hL[stb*hrow + stp] = v;
    }
    __syncthreads();                     // SYNC1: hL staged

    // ---- matvec: acc[8 cols][4 b] over k in [lane*8, lane*8+8) ----
    float acc[8][4];
    #pragma unroll
    for (int ci = 0; ci < 8; ++ci)
      #pragma unroll
      for (int b = 0; b < 4; ++b) acc[ci][b] = 0.0f;
    #pragma unroll
    for (int b = 0; b < 4; ++b){
      const float* hr = &hL[b*hrow];
      float4 h0 = *(const float4*)(hr + p0);
      float4 h1 = *(const float4*)(hr + p1);
      float hv[8] = {h0.x,h0.y,h0.z,h0.w,h1.x,h1.y,h1.z,h1.w};
      #pragma unroll
      for (int j = 0; j < 8; ++j){
        #pragma unroll
        for (int ci = 0; ci < 8; ++ci)
          acc[ci][b] = fmaf(wreg[ci][j], hv[j], acc[ci][b]);
      }
    }

    // ---- value-splitting butterfly: 64 partials/z -> 8, in registers ----
    float v16[16];
    {
      bool hi = (lane & 1);
      #pragma unroll
      for (int i = 0; i < 16; ++i){
        int ci = i >> 2, b = i & 3;
        float keep = hi ? acc[4+ci][b] : acc[ci][b];
        float send = hi ? acc[ci][b]   : acc[4+ci][b];
        v16[i] = keep + __shfl_xor(send, 1);
      }
    }
    float v8[8];
    {
      bool hi = (lane & 2);
      #pragma unroll
      for (int i = 0; i < 8; ++i){
        float keep = hi ? v16[8+i] : v16[i];
        float send = hi ? v16[i]   : v16[8+i];
        v8[i] = keep + __shfl_xor(send, 2);
      }
    }
    float v4[4];
    {
      bool hi = (lane & 4);
      #pragma unroll
      for (int b = 0; b < 4; ++b){
        float keep = hi ? v8[4+b] : v8[b];
        float send = hi ? v8[b]   : v8[4+b];
        v4[b] = keep + __shfl_xor(send, 4);
      }
    }
    {
      int e = ((lane & 1) << 2) | (lane & 2) | ((lane >> 2) & 1);
      float* pw = &part[(lane >> 3)*260 + ((8*w + e) << 2)];
      *(float4*)pw = make_float4(v4[0], v4[1], v4[2], v4[3]);
    }
    __syncthreads();                     // SYNC2: part complete; waves 1-7 go poll next t

    // ---- wave0 tail: reduce 8 partials/z + gates + publish + tag + out ----
    if (tid < 64){
      int jl = tid >> 2, bb = tid & 3;
      float zv[4];
      #pragma unroll
      for (int gi = 0; gi < 4; ++gi){
        int zi = ((gi << 4) | jl) << 2;  // z-local*4
        float s0 = part[0*260 + zi + bb] + part[1*260 + zi + bb];
        float s1 = part[2*260 + zi + bb] + part[3*260 + zi + bb];
        float s2 = part[4*260 + zi + bb] + part[5*260 + zi + bb];
        float s3 = part[6*260 + zi + bb] + part[7*260 + zi + bb];
        zv[gi] = (s0+s1)+(s2+s3) + xz4[gi];
      }
      float dv0 = dv0L[(t << 2) + bb];
      float dv1 = dv1L[(t << 2) + bb];
      float ccand = sigf(zv[1])*c_reg + sigf(zv[0])*tanhfast(zv[2]);
      float hcand = sigf(zv[3])*tanhfast(ccand);
      c_reg = dv0*ccand + dv1*c_reg;
      float hnew = dv0*hcand + dv1*h_reg;
      h_reg = hnew;
      int hk = (m << 4) + jl;
      __hip_atomic_store(hnxt + bb*512 + hk, hnew,
                         __ATOMIC_RELAXED, __HIP_MEMORY_SCOPE_AGENT);
      asm volatile("s_waitcnt vmcnt(0)" ::: "memory");   // drain publish before tag
      if (tid == 0){
        __hip_atomic_store(tags + (g << 5) + m, (unsigned)(t+1),
                           __ATOMIC_RELAXED, __HIP_MEMORY_SCOPE_AGENT);
      }
      out[(size_t)((g << 2) + bb)*(Tz*Hz) + (size_t)t*Hz + hk] = hcand;
    }
    // NOTE: no barrier here. Waves 1-7 are already polling step t+1; wave 0 joins
    // after its tail. hL overwrite (staging t+1) is safe: all hL reads were in the
    // matvec before SYNC2. part overwrite (t+1) happens only after SYNC1(t+1), which
    // needs wave 0's staging — i.e., after wave 0's part reads above.
  }
}

extern "C" void kernel_launch(void* const* d_in, const int* in_sizes, int n_in,
                              void* d_out, int out_size, void* d_ws, size_t ws_size,
                              hipStream_t stream)
{
  const float* x       = (const float*)d_in[0];
  const float* conv1_w = (const float*)d_in[1];
  const float* conv1_b = (const float*)d_in[2];
  const float* conv2_w = (const float*)d_in[3];
  const float* conv2_b = (const float*)d_in[4];
  const float* conv3_w = (const float*)d_in[5];
  const float* conv3_b = (const float*)d_in[6];
  const float* rev_Wx  = (const float*)d_in[7];
  const float* rev_Wh  = (const float*)d_in[8];
  const float* rev_b   = (const float*)d_in[9];
  const float* d0_W    = (const float*)d_in[10];
  const float* d0_b    = (const float*)d_in[11];
  const float* d1_W    = (const float*)d_in[12];
  const float* d1_b    = (const float*)d_in[13];
  const float* cell_Wx = (const float*)d_in[14];
  const float* cell_Wh = (const float*)d_in[15];
  const float* cell_b  = (const float*)d_in[16];
  const float* gumbel  = (const float*)d_in[17];
  float* out = (float*)d_out;

  char* ws = (char*)d_ws;
  size_t off = 0;
  float* xzG  = (float*)(ws + off); off += (size_t)Tz*2048*Bz*4;       // 134 MB
  float* feat = (float*)(ws + off); off += (size_t)Tz*Bz*FCH*4;        // 29 MB
  float* rxw  = (float*)(ws + off); off += (size_t)Tz*Bz*40*4;         // 2.6 MB
  float* hid  = (float*)(ws + off); off += (size_t)Tz*Bz*100*4;        // 6.5 MB
  float* d0a  = (float*)(ws + off); off += (size_t)Tz*Bz*4;
  float* d1a  = (float*)(ws + off); off += (size_t)Tz*Bz*4;
  float* hG   = (float*)(ws + off); off += (size_t)8*2*4*512*4;        // 128 KB
  unsigned int* tags = (unsigned int*)(ws + off); off += 8*32*4;       // 1 KB

  // zero-init: feat row T-1 (ff tail zeros; k_conv writes its x-part), tags
  hipMemsetAsync(feat + (size_t)(Tz-1)*Bz*FCH, 0, Bz*FCH*4, stream);
  hipMemsetAsync(tags, 0, 8*32*4, stream);

  k_conv<<<512, 256, 0, stream>>>(x, conv1_w, conv1_b, conv2_w, conv2_b,
                                  conv3_w, conv3_b, rev_Wx, feat, rxw);
  k_rev<<<32, 64, 0, stream>>>(rxw, rev_Wh, rev_b, feat);
  k_hid<<<512, 256, 0, stream>>>(feat, d0_W, d0_b, hid);
  k_pi<<<256, 128, 0, stream>>>(hid, d1_W, d1_b, gumbel, d0a, d1a);
  k_xz<<<8192, 256, 0, stream>>>(x, cell_Wx, cell_b, xzG);

  k_scan<<<256, 512, 0, stream>>>(cell_Wh, xzG, d0a, d1a, hG, tags, out);
}

// Round 6
// 3219.340 us; speedup vs baseline: 1.2078x; 1.2078x over previous
//
#include <hip/hip_runtime.h>
#include <math.h>

#define Bz 32
#define Tz 512
#define Ez 256
#define Hz 512
#define FCH 446   // 180 conv + 10 rev + 256 x

__device__ __forceinline__ float sigf(float x){ return 1.0f/(1.0f + __expf(-x)); }
__device__ __forceinline__ float tanhfast(float x){ return 1.0f - 2.0f/(__expf(2.0f*x) + 1.0f); }

// ---------------- conv (3 kernels, SAME pad) + rxw = x_rev @ rev_Wx + x-copy into feat ----
__global__ __launch_bounds__(256) void k_conv(
    const float* __restrict__ x,
    const float* __restrict__ w1, const float* __restrict__ b1,
    const float* __restrict__ w2, const float* __restrict__ b2,
    const float* __restrict__ w3, const float* __restrict__ b3,
    const float* __restrict__ rwx,
    float* __restrict__ feat, float* __restrict__ rxw)
{
  __shared__ __align__(16) float xs[256*40];   // xs[e*40 + i] = x[b][t0-2+i], i in 0..35
  int b  = blockIdx.x >> 4;
  int t0 = (blockIdx.x & 15) * 32;
  int tid = threadIdx.x;
  for (int i = 0; i < 36; ++i){
    int t = t0 - 2 + i;
    xs[tid*40 + i] = (t >= 0 && t < Tz) ? x[(b*Tz + t)*Ez + tid] : 0.0f;
  }
  __syncthreads();
  // x-part of d0 input: feat[t][b][190+e] = x[b][t][e]
  for (int i = 0; i < 32; ++i){
    int t = t0 + i;
    feat[((size_t)t*Bz + b)*FCH + 190 + tid] = xs[tid*40 + i + 2];
  }
  int tq = tid & 7, cs = tid >> 3;             // 8 t-quads x 32 c-slots
  float acc[6][4];
  float racc[2][4];
  #pragma unroll
  for (int ci = 0; ci < 6; ++ci){
    int c = cs + 32*ci;
    float bv = 0.0f;
    if (c < 60) bv = b1[c];
    else if (c < 120) bv = b2[c-60];
    else if (c < 180) bv = b3[c-120];
    acc[ci][0]=acc[ci][1]=acc[ci][2]=acc[ci][3]=bv;
  }
  #pragma unroll
  for (int ji = 0; ji < 2; ++ji){ racc[ji][0]=racc[ji][1]=racc[ji][2]=racc[ji][3]=0.0f; }

  for (int e = 0; e < 256; ++e){
    const float* xr = &xs[e*40 + 4*tq];
    float4 wa = *(const float4*)(xr);
    float4 wb = *(const float4*)(xr + 4);
    float wd[8] = {wa.x, wa.y, wa.z, wa.w, wb.x, wb.y, wb.z, wb.w};
    #pragma unroll
    for (int ci = 0; ci < 6; ++ci){
      int c = cs + 32*ci;
      if (c < 60){
        #pragma unroll
        for (int k = 0; k < 3; ++k){
          float wv = w1[(k*256 + e)*60 + c];
          #pragma unroll
          for (int j = 0; j < 4; ++j) acc[ci][j] = fmaf(wd[1 + j + k], wv, acc[ci][j]);
        }
      } else if (c < 120){
        int cc = c - 60;
        #pragma unroll
        for (int k = 0; k < 4; ++k){
          float wv = w2[(k*256 + e)*60 + cc];
          #pragma unroll
          for (int j = 0; j < 4; ++j) acc[ci][j] = fmaf(wd[1 + j + k], wv, acc[ci][j]);
        }
      } else if (c < 180){
        int cc = c - 120;
        #pragma unroll
        for (int k = 0; k < 5; ++k){
          float wv = w3[(k*256 + e)*60 + cc];
          #pragma unroll
          for (int j = 0; j < 4; ++j) acc[ci][j] = fmaf(wd[j + k], wv, acc[ci][j]);
        }
      }
    }
    #pragma unroll
    for (int ji = 0; ji < 2; ++ji){
      int jc = cs + 32*ji;
      if (jc < 40){
        float wv = rwx[e*40 + jc];
        #pragma unroll
        for (int j = 0; j < 4; ++j) racc[ji][j] = fmaf(wd[2 + j], wv, racc[ji][j]);
      }
    }
  }
  #pragma unroll
  for (int ci = 0; ci < 6; ++ci){
    int c = cs + 32*ci;
    if (c < 180){
      #pragma unroll
      for (int j = 0; j < 4; ++j){
        int t = t0 + 4*tq + j;
        if (t >= 1) feat[((size_t)(t-1)*Bz + b)*FCH + c] = acc[ci][j];
      }
    }
  }
  #pragma unroll
  for (int ji = 0; ji < 2; ++ji){
    int jc = cs + 32*ji;
    if (jc < 40){
      #pragma unroll
      for (int j = 0; j < 4; ++j){
        int t = t0 + 4*tq + j;
        rxw[((size_t)(511 - t)*Bz + b)*40 + jc] = racc[ji][j];
      }
    }
  }
}

// ---------------- reverse LSTM (hidden 10), one wave per batch row ----------------
__global__ __launch_bounds__(64) void k_rev(const float* __restrict__ rxw,
    const float* __restrict__ revWh, const float* __restrict__ revb, float* __restrict__ feat){
  int b = blockIdx.x;
  int j = threadIdx.x;
  float wreg[10];
  float bias = 0.0f;
  #pragma unroll
  for (int k = 0; k < 10; ++k) wreg[k] = 0.0f;
  if (j < 40){
    bias = revb[j];
    #pragma unroll
    for (int k = 0; k < 10; ++k) wreg[k] = revWh[k*40 + j];
  }
  float h[10];
  #pragma unroll
  for (int k = 0; k < 10; ++k) h[k] = 0.0f;
  float c = 0.0f;
  for (int s = 0; s < Tz; ++s){
    float z = bias + ((j < 40) ? rxw[(s*Bz + b)*40 + j] : 0.0f);
    #pragma unroll
    for (int k = 0; k < 10; ++k) z = fmaf(h[k], wreg[k], z);
    float a = (j >= 20 && j < 30) ? tanhfast(z) : sigf(z);
    float af = __shfl(a, j + 10);
    float ag = __shfl(a, j + 20);
    float ao = __shfl(a, j + 30);
    if (j < 10) c = af*c + a*ag;
    float hn = ao * tanhfast(c);
    #pragma unroll
    for (int k = 0; k < 10; ++k) h[k] = __shfl(hn, k);
    if (j < 10 && s >= 1) feat[((size_t)(s-1)*Bz + b)*FCH + 180 + j] = hn;
  }
}

// ---------------- hid = relu(feat @ d0_W + d0_b): 32 rows x 100 cols per block ----------------
__global__ __launch_bounds__(256) void k_hid(const float* __restrict__ feat,
    const float* __restrict__ d0W, const float* __restrict__ d0b, float* __restrict__ hid){
  __shared__ __align__(16) float fT[446*36];   // fT[ch*36 + r]
  int r0 = blockIdx.x * 32;
  int tid = threadIdx.x;
  for (int r = 0; r < 32; ++r){
    fT[tid*36 + r] = feat[(size_t)(r0 + r)*FCH + tid];
    if (tid < 190) fT[(tid + 256)*36 + r] = feat[(size_t)(r0 + r)*FCH + tid + 256];
  }
  __syncthreads();
  int cs = tid & 31, rq = tid >> 5;            // 32 c-slots (4 cols each), 8 row-quads
  if (cs < 25){
    float4 accv[4];
    #pragma unroll
    for (int jc = 0; jc < 4; ++jc) accv[jc] = make_float4(0.f,0.f,0.f,0.f);
    for (int k = 0; k < 446; ++k){
      float4 xv = *(const float4*)&fT[k*36 + 4*rq];
      float4 wv = *(const float4*)&d0W[k*100 + 4*cs];
      accv[0].x = fmaf(xv.x, wv.x, accv[0].x); accv[0].y = fmaf(xv.y, wv.x, accv[0].y);
      accv[0].z = fmaf(xv.z, wv.x, accv[0].z); accv[0].w = fmaf(xv.w, wv.x, accv[0].w);
      accv[1].x = fmaf(xv.x, wv.y, accv[1].x); accv[1].y = fmaf(xv.y, wv.y, accv[1].y);
      accv[1].z = fmaf(xv.z, wv.y, accv[1].z); accv[1].w = fmaf(xv.w, wv.y, accv[1].w);
      accv[2].x = fmaf(xv.x, wv.z, accv[2].x); accv[2].y = fmaf(xv.y, wv.z, accv[2].y);
      accv[2].z = fmaf(xv.z, wv.z, accv[2].z); accv[2].w = fmaf(xv.w, wv.z, accv[2].w);
      accv[3].x = fmaf(xv.x, wv.w, accv[3].x); accv[3].y = fmaf(xv.y, wv.w, accv[3].y);
      accv[3].z = fmaf(xv.z, wv.w, accv[3].z); accv[3].w = fmaf(xv.w, wv.w, accv[3].w);
    }
    #pragma unroll
    for (int i = 0; i < 4; ++i){
      int row = r0 + 4*rq + i;
      float4 o;
      float vi[4] = { i==0?accv[0].x:(i==1?accv[0].y:(i==2?accv[0].z:accv[0].w)),
                      i==0?accv[1].x:(i==1?accv[1].y:(i==2?accv[1].z:accv[1].w)),
                      i==0?accv[2].x:(i==1?accv[2].y:(i==2?accv[2].z:accv[2].w)),
                      i==0?accv[3].x:(i==1?accv[3].y:(i==2?accv[3].z:accv[3].w)) };
      o.x = fmaxf(vi[0] + d0b[4*cs+0], 0.0f);
      o.y = fmaxf(vi[1] + d0b[4*cs+1], 0.0f);
      o.z = fmaxf(vi[2] + d0b[4*cs+2], 0.0f);
      o.w = fmaxf(vi[3] + d0b[4*cs+3], 0.0f);
      *(float4*)&hid[(size_t)row*100 + 4*cs] = o;
    }
  }
}

// ---------------- pi + gumbel softmax -> d0,d1 (64 rows per block) ----------------
__global__ __launch_bounds__(128) void k_pi(const float* __restrict__ hid,
    const float* __restrict__ d1W, const float* __restrict__ d1b,
    const float* __restrict__ gum, float* __restrict__ d0a, float* __restrict__ d1a){
  __shared__ float hidL[64*100];
  int r0 = blockIdx.x * 64;
  int tid = threadIdx.x;
  for (int i = 0; i < 50; ++i) hidL[tid + 128*i] = hid[(size_t)r0*100 + tid + 128*i];
  __syncthreads();
  int r = tid >> 1, pp = tid & 1;
  float s = d1b[pp];
  for (int m = 0; m < 100; ++m) s = fmaf(hidL[r*100 + m], d1W[m*2 + pp], s);
  int row = r0 + r;
  float a = (s + gum[row*2 + pp]) / 1e-5f;
  float other = __shfl_xor(a, 1);
  float mx = fmaxf(a, other);
  float ea = expf(a - mx), eb = expf(other - mx);
  float d = ea / (ea + eb);
  if (pp == 0) d0a[row] = d; else d1a[row] = d;
}

// ---------------- xzG[((g*T + t)*2048 + col)*4 + b'] = x[b][t] @ cell_Wx + cell_b ----------
__global__ __launch_bounds__(256) void k_xz(const float* __restrict__ x,
    const float* __restrict__ Wx, const float* __restrict__ cb, float* __restrict__ xzG){
  __shared__ __align__(16) float xT[256*36];   // xT[e*36 + b]
  int t  = blockIdx.x & 511;
  int c0 = (blockIdx.x >> 9) * 128;
  int tid = threadIdx.x;
  for (int b = 0; b < 32; ++b){
    xT[tid*36 + b] = x[(b*Tz + t)*Ez + tid];
  }
  __syncthreads();
  int cs = tid & 31, rq = tid >> 5;            // 32 col-slots (4 cols), 8 batch-quads (=groups)
  float4 accv[4];
  #pragma unroll
  for (int jc = 0; jc < 4; ++jc) accv[jc] = make_float4(0.f,0.f,0.f,0.f);
  float4 wv = *(const float4*)&Wx[c0 + 4*cs];  // e = 0 prefetch
  for (int e = 0; e < 256; ++e){
    float4 wc = wv;
    if (e != 255) wv = *(const float4*)&Wx[(e+1)*2048 + c0 + 4*cs];
    float4 xv = *(const float4*)&xT[e*36 + 4*rq];
    accv[0].x = fmaf(xv.x, wc.x, accv[0].x); accv[0].y = fmaf(xv.y, wc.x, accv[0].y);
    accv[0].z = fmaf(xv.z, wc.x, accv[0].z); accv[0].w = fmaf(xv.w, wc.x, accv[0].w);
    accv[1].x = fmaf(xv.x, wc.y, accv[1].x); accv[1].y = fmaf(xv.y, wc.y, accv[1].y);
    accv[1].z = fmaf(xv.z, wc.y, accv[1].z); accv[1].w = fmaf(xv.w, wc.y, accv[1].w);
    accv[2].x = fmaf(xv.x, wc.z, accv[2].x); accv[2].y = fmaf(xv.y, wc.z, accv[2].y);
    accv[2].z = fmaf(xv.z, wc.z, accv[2].z); accv[2].w = fmaf(xv.w, wc.z, accv[2].w);
    accv[3].x = fmaf(xv.x, wc.w, accv[3].x); accv[3].y = fmaf(xv.y, wc.w, accv[3].y);
    accv[3].z = fmaf(xv.z, wc.w, accv[3].z); accv[3].w = fmaf(xv.w, wc.w, accv[3].w);
  }
  #pragma unroll
  for (int jc = 0; jc < 4; ++jc){
    int col = c0 + 4*cs + jc;
    float bv = cb[col];
    float4 o = accv[jc];
    o.x += bv; o.y += bv; o.z += bv; o.w += bv;
    *(float4*)&xzG[(((size_t)rq*Tz + t)*2048 + col)*4] = o;
  }
}

// ---------------- persistent scan kernel v10: round-0 lockstep + early tag + h_reg ----
// 256 blocks x 512 threads. The round-0 4-barrier lockstep structure is restored
// verbatim (R5's 2-barrier wave0-tail variant measured 1715 -> 2718us: in the
// all-to-all exchange, per-block jitter enters the step time as max over 32
// producers — decoupling waves raises jitter and the convoy pays it every step).
// Two strictly-local changes vs round 0:
//  (1) EARLY TAG: wave 0 publishes h, drains with a wave-local s_waitcnt vmcnt(0)
//      (h-before-tag ordering preserved — mechanism correctness-proven in R5), and
//      tid0 stores the tag BEFORE SYNC4 instead of after it. Consumers in other
//      blocks poll asynchronously, so the tag lands ~300-500 cycles earlier per
//      step; the lockstep barriers are untouched.
//  (2) h_reg: the gate thread's hold value is its own previous hnew — kept in a
//      register, removing the swizzled hL re-read from the gate phase.
__global__ __launch_bounds__(512, 2) void k_scan(
    const float* __restrict__ Wh, const float* __restrict__ xzG,
    const float* __restrict__ d0a, const float* __restrict__ d1a,
    float* __restrict__ hG,              // [8 groups][2 bufs][4*512]
    unsigned int* __restrict__ tags,     // [8][32]
    float* __restrict__ out)
{
  __shared__ __align__(16) float hL[4*520];    // swizzled h, row stride 520
  __shared__ __align__(16) float part[8*260];  // 8 kgroups x 64 cols x 4 b, stride 260
  __shared__ float zL[256];
  __shared__ float hcandL[64];
  __shared__ float dv0L[2048];                 // [t*4 + bb], staged once
  __shared__ float dv1L[2048];

  int tid = threadIdx.x;
  int g = blockIdx.x & 7;
  int m = blockIdx.x >> 3;
  int w = tid >> 6;                      // wave 0..7
  int lane = tid & 63;                   // = kseg

  // one-time: weights into VGPRs straight from Wh[k][col]:
  // wreg[ci][j] = Wh[(lane*8+j)*2048 + colbase + ci], cols contiguous per wave.
  float wreg[8][8];
  {
    int colbase = ((w >> 1) << 9) + (m << 4) + ((w & 1) << 3);
    #pragma unroll
    for (int j = 0; j < 8; ++j){
      const float4* wp = (const float4*)(Wh + (size_t)(lane*8 + j)*2048 + colbase);
      float4 a = wp[0], bq = wp[1];
      wreg[0][j]=a.x;  wreg[1][j]=a.y;  wreg[2][j]=a.z;  wreg[3][j]=a.w;
      wreg[4][j]=bq.x; wreg[5][j]=bq.y; wreg[6][j]=bq.z; wreg[7][j]=bq.w;
    }
  }
  // one-time: gate coefficients to LDS
  for (int i = tid; i < 2048; i += 512){
    int tt = i >> 2, bb = i & 3;
    dv0L[i] = d0a[tt*32 + (g << 2) + bb];
    dv1L[i] = d1a[tt*32 + (g << 2) + bb];
  }

  // swizzled LDS addresses for this lane's two h quads (k = lane*8 .. +8)
  int q0 = 2*lane;
  int sw = (q0 >> 3) & 3;
  int p0 = ((q0  ) ^ sw) << 2;
  int p1 = ((q0+1) ^ sw) << 2;

  // staging role: thread stages quad (b = tid>>7, q = tid&127); producer = q>>2
  int stb = tid >> 7, stq = tid & 127;
  int stp = (stq ^ ((stq >> 3) & 3)) << 2;
  const int hrow = 520;
  const unsigned int* mytag = tags + (g << 5) + (stq >> 2);

  // reducer xz address (tid<256)
  int rcg = tid >> 2, rb = tid & 3;
  int rcol = ((rcg >> 4) << 9) + (m << 4) + (rcg & 15);
  size_t xzbase = ((size_t)g*Tz)*8192 + (size_t)rcol*4 + rb;

  float* hg0 = hG + (size_t)(g*2 + 0) * (4*512);
  float* hg1 = hG + (size_t)(g*2 + 1) * (4*512);

  float c_reg = 0.0f;                    // cell state (tid<64: bb=tid&3, jl=tid>>2)
  float h_reg = 0.0f;                    // own h state (tid<64) — hold == prev hnew

  for (int t = 0; t < Tz; ++t){
    const float* hcur = (t & 1) ? hg1 : hg0;
    float*       hnxt = (t & 1) ? hg0 : hg1;

    // ---- stage group h (gen t): poll own producer's tag, then load its quad ----
    if (t == 0){
      *(float4*)&hL[stb*hrow + stp] = make_float4(0.f,0.f,0.f,0.f);
    } else {
      while (__hip_atomic_load(mytag, __ATOMIC_RELAXED, __HIP_MEMORY_SCOPE_AGENT)
             < (unsigned)t) { }
      const float* src = hcur + stb*512 + stq*4;
      float4 v;
      v.x = __hip_atomic_load(src+0, __ATOMIC_RELAXED, __HIP_MEMORY_SCOPE_AGENT);
      v.y = __hip_atomic_load(src+1, __ATOMIC_RELAXED, __HIP_MEMORY_SCOPE_AGENT);
      v.z = __hip_atomic_load(src+2, __ATOMIC_RELAXED, __HIP_MEMORY_SCOPE_AGENT);
      v.w = __hip_atomic_load(src+3, __ATOMIC_RELAXED, __HIP_MEMORY_SCOPE_AGENT);
      *(float4*)&hL[stb*hrow + stp] = v;
    }
    float xzv = 0.0f;
    if (tid < 256) xzv = xzG[xzbase + (size_t)t*8192];
    __syncthreads();

    // ---- matvec: acc[8 cols][4 b] over k in [lane*8, lane*8+8) ----
    float acc[8][4];
    #pragma unroll
    for (int ci = 0; ci < 8; ++ci)
      #pragma unroll
      for (int b = 0; b < 4; ++b) acc[ci][b] = 0.0f;
    #pragma unroll
    for (int b = 0; b < 4; ++b){
      const float* hr = &hL[b*hrow];
      float4 h0 = *(const float4*)(hr + p0);
      float4 h1 = *(const float4*)(hr + p1);
      float hv[8] = {h0.x,h0.y,h0.z,h0.w,h1.x,h1.y,h1.z,h1.w};
      #pragma unroll
      for (int j = 0; j < 8; ++j){
        #pragma unroll
        for (int ci = 0; ci < 8; ++ci)
          acc[ci][b] = fmaf(wreg[ci][j], hv[j], acc[ci][b]);
      }
    }

    // ---- value-splitting butterfly: 64 partials/z -> 8, in registers ----
    float v16[16];
    {
      bool hi = (lane & 1);
      #pragma unroll
      for (int i = 0; i < 16; ++i){
        int ci = i >> 2, b = i & 3;
        float keep = hi ? acc[4+ci][b] : acc[ci][b];
        float send = hi ? acc[ci][b]   : acc[4+ci][b];
        v16[i] = keep + __shfl_xor(send, 1);
      }
    }
    float v8[8];
    {
      bool hi = (lane & 2);
      #pragma unroll
      for (int i = 0; i < 8; ++i){
        float keep = hi ? v16[8+i] : v16[i];
        float send = hi ? v16[i]   : v16[8+i];
        v8[i] = keep + __shfl_xor(send, 2);
      }
    }
    float v4[4];
    {
      bool hi = (lane & 4);
      #pragma unroll
      for (int b = 0; b < 4; ++b){
        float keep = hi ? v8[4+b] : v8[b];
        float send = hi ? v8[b]   : v8[4+b];
        v4[b] = keep + __shfl_xor(send, 4);
      }
    }
    {
      int e = ((lane & 1) << 2) | (lane & 2) | ((lane >> 2) & 1);
      float* pw = &part[(lane >> 3)*260 + ((8*w + e) << 2)];
      *(float4*)pw = make_float4(v4[0], v4[1], v4[2], v4[3]);
    }
    __syncthreads();

    // ---- final reduce: 8 partials per z ----
    if (tid < 256){
      float s0 = part[0*260 + tid] + part[1*260 + tid];
      float s1 = part[2*260 + tid] + part[3*260 + tid];
      float s2 = part[4*260 + tid] + part[5*260 + tid];
      float s3 = part[6*260 + tid] + part[7*260 + tid];
      zL[tid] = (s0+s1)+(s2+s3) + xzv;
    }
    __syncthreads();

    // ---- gates + publish + EARLY tag (wave 0) ----
    if (tid < 64){
      int jl = tid >> 2, bb = tid & 3;
      float zi = zL[      (jl << 2) + bb];
      float zf = zL[ 64 + (jl << 2) + bb];
      float zg = zL[128 + (jl << 2) + bb];
      float zo = zL[192 + (jl << 2) + bb];
      float dv0 = dv0L[(t << 2) + bb];
      float dv1 = dv1L[(t << 2) + bb];
      int hk = (m << 4) + jl;
      float ccand = sigf(zf)*c_reg + sigf(zi)*tanhfast(zg);
      float hcand = sigf(zo)*tanhfast(ccand);
      c_reg = dv0*ccand + dv1*c_reg;
      float hnew = dv0*hcand + dv1*h_reg;
      h_reg = hnew;
      hcandL[(bb << 4) + jl] = hcand;
      __hip_atomic_store(hnxt + bb*512 + hk, hnew,
                         __ATOMIC_RELAXED, __HIP_MEMORY_SCOPE_AGENT);
      asm volatile("s_waitcnt vmcnt(0)" ::: "memory");   // wave-local: h visible first
      if (tid == 0){
        __hip_atomic_store(tags + (g << 5) + m, (unsigned)(t+1),
                           __ATOMIC_RELAXED, __HIP_MEMORY_SCOPE_AGENT);
      }
    }
    __syncthreads();                     // SYNC4: lockstep preserved

    // out store (wave 1) — off the next-staging path
    if (tid >= 64 && tid < 80){
      int idx = tid - 64; int bb = idx >> 2, q = idx & 3;
      float4 v = *(const float4*)&hcandL[(bb << 4) + 4*q];
      *(float4*)(out + (size_t)((g << 2) + bb)*(Tz*Hz) + (size_t)t*Hz + (m << 4) + 4*q) = v;
    }
  }
}

extern "C" void kernel_launch(void* const* d_in, const int* in_sizes, int n_in,
                              void* d_out, int out_size, void* d_ws, size_t ws_size,
                              hipStream_t stream)
{
  const float* x       = (const float*)d_in[0];
  const float* conv1_w = (const float*)d_in[1];
  const float* conv1_b = (const float*)d_in[2];
  const float* conv2_w = (const float*)d_in[3];
  const float* conv2_b = (const float*)d_in[4];
  const float* conv3_w = (const float*)d_in[5];
  const float* conv3_b = (const float*)d_in[6];
  const float* rev_Wx  = (const float*)d_in[7];
  const float* rev_Wh  = (const float*)d_in[8];
  const float* rev_b   = (const float*)d_in[9];
  const float* d0_W    = (const float*)d_in[10];
  const float* d0_b    = (const float*)d_in[11];
  const float* d1_W    = (const float*)d_in[12];
  const float* d1_b    = (const float*)d_in[13];
  const float* cell_Wx = (const float*)d_in[14];
  const float* cell_Wh = (const float*)d_in[15];
  const float* cell_b  = (const float*)d_in[16];
  const float* gumbel  = (const float*)d_in[17];
  float* out = (float*)d_out;

  char* ws = (char*)d_ws;
  size_t off = 0;
  float* xzG  = (float*)(ws + off); off += (size_t)Tz*2048*Bz*4;       // 134 MB
  float* feat = (float*)(ws + off); off += (size_t)Tz*Bz*FCH*4;        // 29 MB
  float* rxw  = (float*)(ws + off); off += (size_t)Tz*Bz*40*4;         // 2.6 MB
  float* hid  = (float*)(ws + off); off += (size_t)Tz*Bz*100*4;        // 6.5 MB
  float* d0a  = (float*)(ws + off); off += (size_t)Tz*Bz*4;
  float* d1a  = (float*)(ws + off); off += (size_t)Tz*Bz*4;
  float* hG   = (float*)(ws + off); off += (size_t)8*2*4*512*4;        // 128 KB
  unsigned int* tags = (unsigned int*)(ws + off); off += 8*32*4;       // 1 KB

  // zero-init: feat row T-1 (ff tail zeros; k_conv writes its x-part), tags
  hipMemsetAsync(feat + (size_t)(Tz-1)*Bz*FCH, 0, Bz*FCH*4, stream);
  hipMemsetAsync(tags, 0, 8*32*4, stream);

  k_conv<<<512, 256, 0, stream>>>(x, conv1_w, conv1_b, conv2_w, conv2_b,
                                  conv3_w, conv3_b, rev_Wx, feat, rxw);
  k_rev<<<32, 64, 0, stream>>>(rxw, rev_Wh, rev_b, feat);
  k_hid<<<512, 256, 0, stream>>>(feat, d0_W, d0_b, hid);
  k_pi<<<256, 128, 0, stream>>>(hid, d1_W, d1_b, gumbel, d0a, d1a);
  k_xz<<<8192, 256, 0, stream>>>(x, cell_Wx, cell_b, xzG);

  k_scan<<<256, 512, 0, stream>>>(cell_Wh, xzG, d0a, d1a, hG, tags, out);
}

// Round 7
// 3001.907 us; speedup vs baseline: 1.2953x; 1.0724x over previous
//
#include <hip/hip_runtime.h>
#include <math.h>

#define Bz 32
#define Tz 512
#define Ez 256
#define Hz 512
#define FCH 446   // 180 conv + 10 rev + 256 x

__device__ __forceinline__ float sigf(float x){ return 1.0f/(1.0f + __expf(-x)); }
__device__ __forceinline__ float tanhfast(float x){ return 1.0f - 2.0f/(__expf(2.0f*x) + 1.0f); }

// ======================= fused pre-chain kernel =======================
// 256 blocks x 256 threads (grid == CU count -> all blocks co-resident, same
// residency argument as k_scan). Replaces k_conv/k_rev/k_hid/k_pi/k_xz:
//   phase A: each block runs 2 conv units (b,tt); signals cnt[b] (release).
//   phase B: blocks 0..31 poll cnt[b]==16, run the reverse LSTM for batch b
//            (rxw prefetched one step ahead), signal cnt[32].
//   phase C: dynamic ticket (cnt[33]): units 0..2047 = xz (t, col-quarter) —
//            depend only on x, so the 224 non-rev blocks start them while rev
//            runs; units 2048..2559 = fused hid+pi (gated once per block on
//            cnt[32]==32, which transitively implies all conv+rev complete).
// Cross-XCD visibility: producers __threadfence() (wbL2) before the agent-scope
// atomic signal; consumers spin relaxed then __threadfence() (invL2) before
// reading data (Guideline 16 pattern). hid tile lives in LDS only — the global
// hid buffer and the k_pi launch are deleted.

__device__ __forceinline__ void conv_unit(int b, int tt, int tid,
    const float* __restrict__ x,
    const float* __restrict__ w1, const float* __restrict__ b1,
    const float* __restrict__ w2, const float* __restrict__ b2,
    const float* __restrict__ w3, const float* __restrict__ b3,
    const float* __restrict__ rwx,
    float* __restrict__ feat, float* __restrict__ rxw, float* xs)
{
  int t0 = tt * 32;
  for (int i = 0; i < 36; ++i){
    int t = t0 - 2 + i;
    xs[tid*40 + i] = (t >= 0 && t < Tz) ? x[(b*Tz + t)*Ez + tid] : 0.0f;
  }
  __syncthreads();
  for (int i = 0; i < 32; ++i){
    int t = t0 + i;
    feat[((size_t)t*Bz + b)*FCH + 190 + tid] = xs[tid*40 + i + 2];
  }
  int tq = tid & 7, cs = tid >> 3;
  float acc[6][4];
  float racc[2][4];
  #pragma unroll
  for (int ci = 0; ci < 6; ++ci){
    int c = cs + 32*ci;
    float bv = 0.0f;
    if (c < 60) bv = b1[c];
    else if (c < 120) bv = b2[c-60];
    else if (c < 180) bv = b3[c-120];
    acc[ci][0]=acc[ci][1]=acc[ci][2]=acc[ci][3]=bv;
  }
  #pragma unroll
  for (int ji = 0; ji < 2; ++ji){ racc[ji][0]=racc[ji][1]=racc[ji][2]=racc[ji][3]=0.0f; }

  for (int e = 0; e < 256; ++e){
    const float* xr = &xs[e*40 + 4*tq];
    float4 wa = *(const float4*)(xr);
    float4 wb = *(const float4*)(xr + 4);
    float wd[8] = {wa.x, wa.y, wa.z, wa.w, wb.x, wb.y, wb.z, wb.w};
    #pragma unroll
    for (int ci = 0; ci < 6; ++ci){
      int c = cs + 32*ci;
      if (c < 60){
        #pragma unroll
        for (int k = 0; k < 3; ++k){
          float wv = w1[(k*256 + e)*60 + c];
          #pragma unroll
          for (int j = 0; j < 4; ++j) acc[ci][j] = fmaf(wd[1 + j + k], wv, acc[ci][j]);
        }
      } else if (c < 120){
        int cc = c - 60;
        #pragma unroll
        for (int k = 0; k < 4; ++k){
          float wv = w2[(k*256 + e)*60 + cc];
          #pragma unroll
          for (int j = 0; j < 4; ++j) acc[ci][j] = fmaf(wd[1 + j + k], wv, acc[ci][j]);
        }
      } else if (c < 180){
        int cc = c - 120;
        #pragma unroll
        for (int k = 0; k < 5; ++k){
          float wv = w3[(k*256 + e)*60 + cc];
          #pragma unroll
          for (int j = 0; j < 4; ++j) acc[ci][j] = fmaf(wd[j + k], wv, acc[ci][j]);
        }
      }
    }
    #pragma unroll
    for (int ji = 0; ji < 2; ++ji){
      int jc = cs + 32*ji;
      if (jc < 40){
        float wv = rwx[e*40 + jc];
        #pragma unroll
        for (int j = 0; j < 4; ++j) racc[ji][j] = fmaf(wd[2 + j], wv, racc[ji][j]);
      }
    }
  }
  #pragma unroll
  for (int ci = 0; ci < 6; ++ci){
    int c = cs + 32*ci;
    if (c < 180){
      #pragma unroll
      for (int j = 0; j < 4; ++j){
        int t = t0 + 4*tq + j;
        if (t >= 1) feat[((size_t)(t-1)*Bz + b)*FCH + c] = acc[ci][j];
      }
    }
  }
  #pragma unroll
  for (int ji = 0; ji < 2; ++ji){
    int jc = cs + 32*ji;
    if (jc < 40){
      #pragma unroll
      for (int j = 0; j < 4; ++j){
        int t = t0 + 4*tq + j;
        rxw[((size_t)(511 - t)*Bz + b)*40 + jc] = racc[ji][j];
      }
    }
  }
  __syncthreads();   // xs free for reuse; all stores drained (vmcnt) per wave
}

__device__ __forceinline__ void rev_unit(int b, int j,
    const float* __restrict__ rxw, const float* __restrict__ revWh,
    const float* __restrict__ revb, float* __restrict__ feat)
{
  float wreg[10];
  float bias = 0.0f;
  #pragma unroll
  for (int k = 0; k < 10; ++k) wreg[k] = 0.0f;
  if (j < 40){
    bias = revb[j];
    #pragma unroll
    for (int k = 0; k < 10; ++k) wreg[k] = revWh[k*40 + j];
  }
  float h[10];
  #pragma unroll
  for (int k = 0; k < 10; ++k) h[k] = 0.0f;
  float c = 0.0f;
  float zin = (j < 40) ? rxw[(0*Bz + b)*40 + j] : 0.0f;   // prefetch s=0
  for (int s = 0; s < Tz; ++s){
    float zcur = zin;
    if (s < Tz-1 && j < 40) zin = rxw[((s+1)*Bz + b)*40 + j];  // hide L2 latency
    float z = bias + zcur;
    #pragma unroll
    for (int k = 0; k < 10; ++k) z = fmaf(h[k], wreg[k], z);
    float a = (j >= 20 && j < 30) ? tanhfast(z) : sigf(z);
    float af = __shfl(a, j + 10);
    float ag = __shfl(a, j + 20);
    float ao = __shfl(a, j + 30);
    if (j < 10) c = af*c + a*ag;
    float hn = ao * tanhfast(c);
    #pragma unroll
    for (int k = 0; k < 10; ++k) h[k] = __shfl(hn, k);
    if (j < 10 && s >= 1) feat[((size_t)(s-1)*Bz + b)*FCH + 180 + j] = hn;
  }
}

__device__ __forceinline__ void hidpi_unit(int t, int tid,
    const float* __restrict__ feat,
    const float* __restrict__ d0W, const float* __restrict__ d0b,
    const float* __restrict__ d1W, const float* __restrict__ d1b,
    const float* __restrict__ gum,
    float* __restrict__ d0a, float* __restrict__ d1a,
    float* fT, float* hidT)
{
  size_t r0 = (size_t)t * 32;
  for (int r = 0; r < 32; ++r){
    fT[tid*36 + r] = feat[(r0 + r)*FCH + tid];
    if (tid < 190) fT[(tid + 256)*36 + r] = feat[(r0 + r)*FCH + tid + 256];
  }
  __syncthreads();
  int cs = tid & 31, rq = tid >> 5;
  if (cs < 25){
    float4 accv[4];
    #pragma unroll
    for (int jc = 0; jc < 4; ++jc) accv[jc] = make_float4(0.f,0.f,0.f,0.f);
    for (int k = 0; k < 446; ++k){
      float4 xv = *(const float4*)&fT[k*36 + 4*rq];
      float4 wv = *(const float4*)&d0W[k*100 + 4*cs];
      accv[0].x = fmaf(xv.x, wv.x, accv[0].x); accv[0].y = fmaf(xv.y, wv.x, accv[0].y);
      accv[0].z = fmaf(xv.z, wv.x, accv[0].z); accv[0].w = fmaf(xv.w, wv.x, accv[0].w);
      accv[1].x = fmaf(xv.x, wv.y, accv[1].x); accv[1].y = fmaf(xv.y, wv.y, accv[1].y);
      accv[1].z = fmaf(xv.z, wv.y, accv[1].z); accv[1].w = fmaf(xv.w, wv.y, accv[1].w);
      accv[2].x = fmaf(xv.x, wv.z, accv[2].x); accv[2].y = fmaf(xv.y, wv.z, accv[2].y);
      accv[2].z = fmaf(xv.z, wv.z, accv[2].z); accv[2].w = fmaf(xv.w, wv.z, accv[2].w);
      accv[3].x = fmaf(xv.x, wv.w, accv[3].x); accv[3].y = fmaf(xv.y, wv.w, accv[3].y);
      accv[3].z = fmaf(xv.z, wv.w, accv[3].z); accv[3].w = fmaf(xv.w, wv.w, accv[3].w);
    }
    #pragma unroll
    for (int i = 0; i < 4; ++i){
      int rl = 4*rq + i;
      float4 o;
      float vi[4] = { i==0?accv[0].x:(i==1?accv[0].y:(i==2?accv[0].z:accv[0].w)),
                      i==0?accv[1].x:(i==1?accv[1].y:(i==2?accv[1].z:accv[1].w)),
                      i==0?accv[2].x:(i==1?accv[2].y:(i==2?accv[2].z:accv[2].w)),
                      i==0?accv[3].x:(i==1?accv[3].y:(i==2?accv[3].z:accv[3].w)) };
      o.x = fmaxf(vi[0] + d0b[4*cs+0], 0.0f);
      o.y = fmaxf(vi[1] + d0b[4*cs+1], 0.0f);
      o.z = fmaxf(vi[2] + d0b[4*cs+2], 0.0f);
      o.w = fmaxf(vi[3] + d0b[4*cs+3], 0.0f);
      *(float4*)&hidT[rl*104 + 4*cs] = o;     // stride 104: 416 B rows, 16B-aligned
    }
  }
  __syncthreads();
  if (tid < 64){
    int r = tid >> 1, pp = tid & 1;
    float s = d1b[pp];
    for (int m2 = 0; m2 < 100; ++m2) s = fmaf(hidT[r*104 + m2], d1W[m2*2 + pp], s);
    size_t row = r0 + r;
    float a = (s + gum[row*2 + pp]) / 1e-5f;
    float other = __shfl_xor(a, 1);
    float mx = fmaxf(a, other);
    float ea = expf(a - mx), eb = expf(other - mx);
    float d = ea / (ea + eb);
    if (pp == 0) d0a[row] = d; else d1a[row] = d;
  }
  __syncthreads();
}

__device__ __forceinline__ void xz_unit(int t, int q, int tid,
    const float* __restrict__ x, const float* __restrict__ Wx,
    const float* __restrict__ cb, float* __restrict__ xzG, float* xT)
{
  for (int bb = 0; bb < 32; ++bb)
    xT[tid*36 + bb] = x[(bb*Tz + t)*Ez + tid];
  __syncthreads();
  int cs = tid & 31, rq = tid >> 5;
  for (int c0i = 4*q; c0i < 4*q + 4; ++c0i){
    int c0 = c0i * 128;
    float4 accv[4];
    #pragma unroll
    for (int jc = 0; jc < 4; ++jc) accv[jc] = make_float4(0.f,0.f,0.f,0.f);
    float4 wv = *(const float4*)&Wx[c0 + 4*cs];
    for (int e = 0; e < 256; ++e){
      float4 wc = wv;
      if (e != 255) wv = *(const float4*)&Wx[(e+1)*2048 + c0 + 4*cs];
      float4 xv = *(const float4*)&xT[e*36 + 4*rq];
      accv[0].x = fmaf(xv.x, wc.x, accv[0].x); accv[0].y = fmaf(xv.y, wc.x, accv[0].y);
      accv[0].z = fmaf(xv.z, wc.x, accv[0].z); accv[0].w = fmaf(xv.w, wc.x, accv[0].w);
      accv[1].x = fmaf(xv.x, wc.y, accv[1].x); accv[1].y = fmaf(xv.y, wc.y, accv[1].y);
      accv[1].z = fmaf(xv.z, wc.y, accv[1].z); accv[1].w = fmaf(xv.w, wc.y, accv[1].w);
      accv[2].x = fmaf(xv.x, wc.z, accv[2].x); accv[2].y = fmaf(xv.y, wc.z, accv[2].y);
      accv[2].z = fmaf(xv.z, wc.z, accv[2].z); accv[2].w = fmaf(xv.w, wc.z, accv[2].w);
      accv[3].x = fmaf(xv.x, wc.w, accv[3].x); accv[3].y = fmaf(xv.y, wc.w, accv[3].y);
      accv[3].z = fmaf(xv.z, wc.w, accv[3].z); accv[3].w = fmaf(xv.w, wc.w, accv[3].w);
    }
    #pragma unroll
    for (int jc = 0; jc < 4; ++jc){
      int col = c0 + 4*cs + jc;
      float bv = cb[col];
      float4 o = accv[jc];
      o.x += bv; o.y += bv; o.z += bv; o.w += bv;
      *(float4*)&xzG[(((size_t)rq*Tz + t)*2048 + col)*4] = o;
    }
  }
  __syncthreads();
}

__global__ __launch_bounds__(256) void k_pre(
    const float* __restrict__ x,
    const float* __restrict__ w1, const float* __restrict__ b1,
    const float* __restrict__ w2, const float* __restrict__ b2,
    const float* __restrict__ w3, const float* __restrict__ b3,
    const float* __restrict__ revWx, const float* __restrict__ revWh,
    const float* __restrict__ revb,
    const float* __restrict__ d0W, const float* __restrict__ d0b,
    const float* __restrict__ d1W, const float* __restrict__ d1b,
    const float* __restrict__ Wx, const float* __restrict__ cbias,
    const float* __restrict__ gum,
    float* __restrict__ feat, float* __restrict__ rxw,
    float* __restrict__ d0a, float* __restrict__ d1a,
    float* __restrict__ xzG,
    unsigned int* __restrict__ cnt)   // cnt[0..31]=conv per-b, cnt[32]=rev, cnt[33]=ticket
{
  __shared__ __align__(16) float sm[19384];   // conv xs 10240 | xz xT 9216 | hid fT 16056 + hidT 3328
  __shared__ unsigned smu;
  int tid = threadIdx.x, bid = blockIdx.x;

  // ---- phase A: conv units {bid, bid+256} ----
  for (int u = bid; u < 512; u += 256){
    conv_unit(u >> 4, u & 15, tid, x, w1, b1, w2, b2, w3, b3, revWx, feat, rxw, sm);
    if (tid == 0){
      __threadfence();            // wbL2: feat/rxw visible device-wide before signal
      __hip_atomic_fetch_add(&cnt[u >> 4], 1u, __ATOMIC_RELAXED, __HIP_MEMORY_SCOPE_AGENT);
    }
  }

  // ---- phase B: rev (blocks 0..31 only; others fall through to the ticket) ----
  if (bid < 32){
    while (__hip_atomic_load(&cnt[bid], __ATOMIC_RELAXED, __HIP_MEMORY_SCOPE_AGENT) < 16u) {}
    __threadfence();              // invL2: fresh rxw
    __syncthreads();
    if (tid < 64) rev_unit(bid, tid, rxw, revWh, revb, feat);
    __syncthreads();
    if (tid == 0){
      __threadfence();
      __hip_atomic_fetch_add(&cnt[32], 1u, __ATOMIC_RELAXED, __HIP_MEMORY_SCOPE_AGENT);
    }
  }

  // ---- phase C: dynamic ticket — 2048 xz units then 512 hid+pi units ----
  bool gated = false;
  for (;;){
    if (tid == 0)
      smu = __hip_atomic_fetch_add(&cnt[33], 1u, __ATOMIC_RELAXED, __HIP_MEMORY_SCOPE_AGENT);
    __syncthreads();
    unsigned u = smu;
    if (u >= 2560u) break;
    if (u < 2048u){
      xz_unit((int)(u >> 2), (int)(u & 3), tid, x, Wx, cbias, xzG, sm);
    } else {
      if (!gated){
        while (__hip_atomic_load(&cnt[32], __ATOMIC_RELAXED, __HIP_MEMORY_SCOPE_AGENT) < 32u) {}
        __threadfence();          // invL2: fresh feat (conv+rev)
        __syncthreads();
        gated = true;
      }
      hidpi_unit((int)(u - 2048u), tid, feat, d0W, d0b, d1W, d1b, gum,
                 d0a, d1a, sm, sm + 16056);
    }
  }
}

// ---------------- persistent scan kernel: round-0 lockstep (verified 1715us) + h_reg ----
// Exact round-0 structure: 4-barrier lockstep, tag published by tid0 AFTER the final
// barrier (single implicit vmcnt drain on the critical path — R6's early-tag variant
// added a second serial drain and cost +145us). Only change vs round 0: the gate
// thread's hold value is its own previous hnew, kept in h_reg (deletes the swizzled
// hL re-read; no ordering change).
__global__ __launch_bounds__(512, 2) void k_scan(
    const float* __restrict__ Wh, const float* __restrict__ xzG,
    const float* __restrict__ d0a, const float* __restrict__ d1a,
    float* __restrict__ hG,              // [8 groups][2 bufs][4*512]
    unsigned int* __restrict__ tags,     // [8][32]
    float* __restrict__ out)
{
  __shared__ __align__(16) float hL[4*520];    // swizzled h, row stride 520
  __shared__ __align__(16) float part[8*260];  // 8 kgroups x 64 cols x 4 b, stride 260
  __shared__ float zL[256];
  __shared__ float hcandL[64];
  __shared__ float dv0L[2048];                 // [t*4 + bb], staged once
  __shared__ float dv1L[2048];

  int tid = threadIdx.x;
  int g = blockIdx.x & 7;
  int m = blockIdx.x >> 3;
  int w = tid >> 6;                      // wave 0..7
  int lane = tid & 63;                   // = kseg

  float wreg[8][8];
  {
    int colbase = ((w >> 1) << 9) + (m << 4) + ((w & 1) << 3);
    #pragma unroll
    for (int j = 0; j < 8; ++j){
      const float4* wp = (const float4*)(Wh + (size_t)(lane*8 + j)*2048 + colbase);
      float4 a = wp[0], bq = wp[1];
      wreg[0][j]=a.x;  wreg[1][j]=a.y;  wreg[2][j]=a.z;  wreg[3][j]=a.w;
      wreg[4][j]=bq.x; wreg[5][j]=bq.y; wreg[6][j]=bq.z; wreg[7][j]=bq.w;
    }
  }
  for (int i = tid; i < 2048; i += 512){
    int tt = i >> 2, bb = i & 3;
    dv0L[i] = d0a[tt*32 + (g << 2) + bb];
    dv1L[i] = d1a[tt*32 + (g << 2) + bb];
  }

  int q0 = 2*lane;
  int sw = (q0 >> 3) & 3;
  int p0 = ((q0  ) ^ sw) << 2;
  int p1 = ((q0+1) ^ sw) << 2;

  int stb = tid >> 7, stq = tid & 127;
  int stp = (stq ^ ((stq >> 3) & 3)) << 2;
  const int hrow = 520;
  const unsigned int* mytag = tags + (g << 5) + (stq >> 2);

  int rcg = tid >> 2, rb = tid & 3;
  int rcol = ((rcg >> 4) << 9) + (m << 4) + (rcg & 15);
  size_t xzbase = ((size_t)g*Tz)*8192 + (size_t)rcol*4 + rb;

  float* hg0 = hG + (size_t)(g*2 + 0) * (4*512);
  float* hg1 = hG + (size_t)(g*2 + 1) * (4*512);

  float c_reg = 0.0f;                    // cell state (tid<64: bb=tid&3, jl=tid>>2)
  float h_reg = 0.0f;                    // own h state (tid<64) — hold == prev hnew

  for (int t = 0; t < Tz; ++t){
    const float* hcur = (t & 1) ? hg1 : hg0;
    float*       hnxt = (t & 1) ? hg0 : hg1;

    // ---- stage group h (gen t): poll own producer's tag, then load its quad ----
    if (t == 0){
      *(float4*)&hL[stb*hrow + stp] = make_float4(0.f,0.f,0.f,0.f);
    } else {
      while (__hip_atomic_load(mytag, __ATOMIC_RELAXED, __HIP_MEMORY_SCOPE_AGENT)
             < (unsigned)t) { }
      const float* src = hcur + stb*512 + stq*4;
      float4 v;
      v.x = __hip_atomic_load(src+0, __ATOMIC_RELAXED, __HIP_MEMORY_SCOPE_AGENT);
      v.y = __hip_atomic_load(src+1, __ATOMIC_RELAXED, __HIP_MEMORY_SCOPE_AGENT);
      v.z = __hip_atomic_load(src+2, __ATOMIC_RELAXED, __HIP_MEMORY_SCOPE_AGENT);
      v.w = __hip_atomic_load(src+3, __ATOMIC_RELAXED, __HIP_MEMORY_SCOPE_AGENT);
      *(float4*)&hL[stb*hrow + stp] = v;
    }
    float xzv = 0.0f;
    if (tid < 256) xzv = xzG[xzbase + (size_t)t*8192];
    __syncthreads();

    // ---- matvec: acc[8 cols][4 b] over k in [lane*8, lane*8+8) ----
    float acc[8][4];
    #pragma unroll
    for (int ci = 0; ci < 8; ++ci)
      #pragma unroll
      for (int b = 0; b < 4; ++b) acc[ci][b] = 0.0f;
    #pragma unroll
    for (int b = 0; b < 4; ++b){
      const float* hr = &hL[b*hrow];
      float4 h0 = *(const float4*)(hr + p0);
      float4 h1 = *(const float4*)(hr + p1);
      float hv[8] = {h0.x,h0.y,h0.z,h0.w,h1.x,h1.y,h1.z,h1.w};
      #pragma unroll
      for (int j = 0; j < 8; ++j){
        #pragma unroll
        for (int ci = 0; ci < 8; ++ci)
          acc[ci][b] = fmaf(wreg[ci][j], hv[j], acc[ci][b]);
      }
    }

    // ---- value-splitting butterfly: 64 partials/z -> 8, in registers ----
    float v16[16];
    {
      bool hi = (lane & 1);
      #pragma unroll
      for (int i = 0; i < 16; ++i){
        int ci = i >> 2, b = i & 3;
        float keep = hi ? acc[4+ci][b] : acc[ci][b];
        float send = hi ? acc[ci][b]   : acc[4+ci][b];
        v16[i] = keep + __shfl_xor(send, 1);
      }
    }
    float v8[8];
    {
      bool hi = (lane & 2);
      #pragma unroll
      for (int i = 0; i < 8; ++i){
        float keep = hi ? v16[8+i] : v16[i];
        float send = hi ? v16[i]   : v16[8+i];
        v8[i] = keep + __shfl_xor(send, 2);
      }
    }
    float v4[4];
    {
      bool hi = (lane & 4);
      #pragma unroll
      for (int b = 0; b < 4; ++b){
        float keep = hi ? v8[4+b] : v8[b];
        float send = hi ? v8[b]   : v8[4+b];
        v4[b] = keep + __shfl_xor(send, 4);
      }
    }
    {
      int e = ((lane & 1) << 2) | (lane & 2) | ((lane >> 2) & 1);
      float* pw = &part[(lane >> 3)*260 + ((8*w + e) << 2)];
      *(float4*)pw = make_float4(v4[0], v4[1], v4[2], v4[3]);
    }
    __syncthreads();

    // ---- final reduce: 8 partials per z ----
    if (tid < 256){
      float s0 = part[0*260 + tid] + part[1*260 + tid];
      float s1 = part[2*260 + tid] + part[3*260 + tid];
      float s2 = part[4*260 + tid] + part[5*260 + tid];
      float s3 = part[6*260 + tid] + part[7*260 + tid];
      zL[tid] = (s0+s1)+(s2+s3) + xzv;
    }
    __syncthreads();

    // ---- gates + publish (wave 0) ----
    if (tid < 64){
      int jl = tid >> 2, bb = tid & 3;
      float zi = zL[      (jl << 2) + bb];
      float zf = zL[ 64 + (jl << 2) + bb];
      float zg = zL[128 + (jl << 2) + bb];
      float zo = zL[192 + (jl << 2) + bb];
      float dv0 = dv0L[(t << 2) + bb];
      float dv1 = dv1L[(t << 2) + bb];
      int hk = (m << 4) + jl;
      float ccand = sigf(zf)*c_reg + sigf(zi)*tanhfast(zg);
      float hcand = sigf(zo)*tanhfast(ccand);
      c_reg = dv0*ccand + dv1*c_reg;
      float hnew = dv0*hcand + dv1*h_reg;
      h_reg = hnew;
      hcandL[(bb << 4) + jl] = hcand;
      __hip_atomic_store(hnxt + bb*512 + hk, hnew,
                         __ATOMIC_RELAXED, __HIP_MEMORY_SCOPE_AGENT);
    }
    __syncthreads();                     // drains wave 0's publish (vmcnt) in all waves

    // tag publish (tid0) + out store (wave 1) — both off the next-staging path
    if (tid == 0){
      __hip_atomic_store(tags + (g << 5) + m, (unsigned)(t+1),
                         __ATOMIC_RELAXED, __HIP_MEMORY_SCOPE_AGENT);
    }
    if (tid >= 64 && tid < 80){
      int idx = tid - 64; int bb = idx >> 2, q = idx & 3;
      float4 v = *(const float4*)&hcandL[(bb << 4) + 4*q];
      *(float4*)(out + (size_t)((g << 2) + bb)*(Tz*Hz) + (size_t)t*Hz + (m << 4) + 4*q) = v;
    }
  }
}

extern "C" void kernel_launch(void* const* d_in, const int* in_sizes, int n_in,
                              void* d_out, int out_size, void* d_ws, size_t ws_size,
                              hipStream_t stream)
{
  const float* x       = (const float*)d_in[0];
  const float* conv1_w = (const float*)d_in[1];
  const float* conv1_b = (const float*)d_in[2];
  const float* conv2_w = (const float*)d_in[3];
  const float* conv2_b = (const float*)d_in[4];
  const float* conv3_w = (const float*)d_in[5];
  const float* conv3_b = (const float*)d_in[6];
  const float* rev_Wx  = (const float*)d_in[7];
  const float* rev_Wh  = (const float*)d_in[8];
  const float* rev_b   = (const float*)d_in[9];
  const float* d0_W    = (const float*)d_in[10];
  const float* d0_b    = (const float*)d_in[11];
  const float* d1_W    = (const float*)d_in[12];
  const float* d1_b    = (const float*)d_in[13];
  const float* cell_Wx = (const float*)d_in[14];
  const float* cell_Wh = (const float*)d_in[15];
  const float* cell_b  = (const float*)d_in[16];
  const float* gumbel  = (const float*)d_in[17];
  float* out = (float*)d_out;

  char* ws = (char*)d_ws;
  size_t off = 0;
  float* xzG  = (float*)(ws + off); off += (size_t)Tz*2048*Bz*4;       // 134 MB
  float* feat = (float*)(ws + off); off += (size_t)Tz*Bz*FCH*4;        // 29 MB
  float* rxw  = (float*)(ws + off); off += (size_t)Tz*Bz*40*4;         // 2.6 MB
  float* d0a  = (float*)(ws + off); off += (size_t)Tz*Bz*4;
  float* d1a  = (float*)(ws + off); off += (size_t)Tz*Bz*4;
  float* hG   = (float*)(ws + off); off += (size_t)8*2*4*512*4;        // 128 KB
  unsigned int* tags = (unsigned int*)(ws + off); off += 8*32*4;       // 1 KB
  unsigned int* cnt  = (unsigned int*)(ws + off); off += 64*4;         // sync counters

  // zero-init: feat row T-1 (ff tail zeros; conv writes its x-part), tags + counters
  hipMemsetAsync(feat + (size_t)(Tz-1)*Bz*FCH, 0, Bz*FCH*4, stream);
  hipMemsetAsync(tags, 0, 8*32*4 + 64*4, stream);

  k_pre<<<256, 256, 0, stream>>>(x, conv1_w, conv1_b, conv2_w, conv2_b,
                                 conv3_w, conv3_b, rev_Wx, rev_Wh, rev_b,
                                 d0_W, d0_b, d1_W, d1_b, cell_Wx, cell_b, gumbel,
                                 feat, rxw, d0a, d1a, xzG, cnt);

  k_scan<<<256, 512, 0, stream>>>(cell_Wh, xzG, d0a, d1a, hG, tags, out);
}

// Round 10
// 2909.356 us; speedup vs baseline: 1.3365x; 1.0318x over previous
//
#include <hip/hip_runtime.h>
#include <math.h>

#define Bz 32
#define Tz 512
#define Ez 256
#define Hz 512
#define FCH 446   // 180 conv + 10 rev + 256 x

__device__ __forceinline__ float sigf(float x){ return 1.0f/(1.0f + __expf(-x)); }
__device__ __forceinline__ float tanhfast(float x){ return 1.0f - 2.0f/(__expf(2.0f*x) + 1.0f); }

// ---------------- conv (3 kernels, SAME pad) + rxw = x_rev @ rev_Wx + x-copy into feat ----
__global__ __launch_bounds__(256) void k_conv(
    const float* __restrict__ x,
    const float* __restrict__ w1, const float* __restrict__ b1,
    const float* __restrict__ w2, const float* __restrict__ b2,
    const float* __restrict__ w3, const float* __restrict__ b3,
    const float* __restrict__ rwx,
    float* __restrict__ feat, float* __restrict__ rxw)
{
  __shared__ __align__(16) float xs[256*40];   // xs[e*40 + i] = x[b][t0-2+i], i in 0..35
  int b  = blockIdx.x >> 4;
  int t0 = (blockIdx.x & 15) * 32;
  int tid = threadIdx.x;
  for (int i = 0; i < 36; ++i){
    int t = t0 - 2 + i;
    xs[tid*40 + i] = (t >= 0 && t < Tz) ? x[(b*Tz + t)*Ez + tid] : 0.0f;
  }
  __syncthreads();
  // x-part of d0 input: feat[t][b][190+e] = x[b][t][e]
  for (int i = 0; i < 32; ++i){
    int t = t0 + i;
    feat[((size_t)t*Bz + b)*FCH + 190 + tid] = xs[tid*40 + i + 2];
  }
  int tq = tid & 7, cs = tid >> 3;             // 8 t-quads x 32 c-slots
  float acc[6][4];
  float racc[2][4];
  #pragma unroll
  for (int ci = 0; ci < 6; ++ci){
    int c = cs + 32*ci;
    float bv = 0.0f;
    if (c < 60) bv = b1[c];
    else if (c < 120) bv = b2[c-60];
    else if (c < 180) bv = b3[c-120];
    acc[ci][0]=acc[ci][1]=acc[ci][2]=acc[ci][3]=bv;
  }
  #pragma unroll
  for (int ji = 0; ji < 2; ++ji){ racc[ji][0]=racc[ji][1]=racc[ji][2]=racc[ji][3]=0.0f; }

  for (int e = 0; e < 256; ++e){
    const float* xr = &xs[e*40 + 4*tq];
    float4 wa = *(const float4*)(xr);
    float4 wb = *(const float4*)(xr + 4);
    float wd[8] = {wa.x, wa.y, wa.z, wa.w, wb.x, wb.y, wb.z, wb.w};
    #pragma unroll
    for (int ci = 0; ci < 6; ++ci){
      int c = cs + 32*ci;
      if (c < 60){
        #pragma unroll
        for (int k = 0; k < 3; ++k){
          float wv = w1[(k*256 + e)*60 + c];
          #pragma unroll
          for (int j = 0; j < 4; ++j) acc[ci][j] = fmaf(wd[1 + j + k], wv, acc[ci][j]);
        }
      } else if (c < 120){
        int cc = c - 60;
        #pragma unroll
        for (int k = 0; k < 4; ++k){
          float wv = w2[(k*256 + e)*60 + cc];
          #pragma unroll
          for (int j = 0; j < 4; ++j) acc[ci][j] = fmaf(wd[1 + j + k], wv, acc[ci][j]);
        }
      } else if (c < 180){
        int cc = c - 120;
        #pragma unroll
        for (int k = 0; k < 5; ++k){
          float wv = w3[(k*256 + e)*60 + cc];
          #pragma unroll
          for (int j = 0; j < 4; ++j) acc[ci][j] = fmaf(wd[j + k], wv, acc[ci][j]);
        }
      }
    }
    #pragma unroll
    for (int ji = 0; ji < 2; ++ji){
      int jc = cs + 32*ji;
      if (jc < 40){
        float wv = rwx[e*40 + jc];
        #pragma unroll
        for (int j = 0; j < 4; ++j) racc[ji][j] = fmaf(wd[2 + j], wv, racc[ji][j]);
      }
    }
  }
  #pragma unroll
  for (int ci = 0; ci < 6; ++ci){
    int c = cs + 32*ci;
    if (c < 180){
      #pragma unroll
      for (int j = 0; j < 4; ++j){
        int t = t0 + 4*tq + j;
        if (t >= 1) feat[((size_t)(t-1)*Bz + b)*FCH + c] = acc[ci][j];
      }
    }
  }
  #pragma unroll
  for (int ji = 0; ji < 2; ++ji){
    int jc = cs + 32*ji;
    if (jc < 40){
      #pragma unroll
      for (int j = 0; j < 4; ++j){
        int t = t0 + 4*tq + j;
        rxw[((size_t)(511 - t)*Bz + b)*40 + jc] = racc[ji][j];
      }
    }
  }
}

// ---------------- reverse LSTM (hidden 10), one wave per batch row ----------------
__global__ __launch_bounds__(64) void k_rev(const float* __restrict__ rxw,
    const float* __restrict__ revWh, const float* __restrict__ revb, float* __restrict__ feat){
  int b = blockIdx.x;
  int j = threadIdx.x;
  float wreg[10];
  float bias = 0.0f;
  #pragma unroll
  for (int k = 0; k < 10; ++k) wreg[k] = 0.0f;
  if (j < 40){
    bias = revb[j];
    #pragma unroll
    for (int k = 0; k < 10; ++k) wreg[k] = revWh[k*40 + j];
  }
  float h[10];
  #pragma unroll
  for (int k = 0; k < 10; ++k) h[k] = 0.0f;
  float c = 0.0f;
  for (int s = 0; s < Tz; ++s){
    float z = bias + ((j < 40) ? rxw[(s*Bz + b)*40 + j] : 0.0f);
    #pragma unroll
    for (int k = 0; k < 10; ++k) z = fmaf(h[k], wreg[k], z);
    float a = (j >= 20 && j < 30) ? tanhfast(z) : sigf(z);
    float af = __shfl(a, j + 10);
    float ag = __shfl(a, j + 20);
    float ao = __shfl(a, j + 30);
    if (j < 10) c = af*c + a*ag;
    float hn = ao * tanhfast(c);
    #pragma unroll
    for (int k = 0; k < 10; ++k) h[k] = __shfl(hn, k);
    if (j < 10 && s >= 1) feat[((size_t)(s-1)*Bz + b)*FCH + 180 + j] = hn;
  }
}

// ------- fused hid+pi: hid tile lives in LDS only; d0a/d1a written directly -------
// 512 blocks x 256 threads, 32 rows each. Deletes the 6.5 MB hid buffer round trip
// and the k_pi launch. LDS 77.5 KB -> 2 blocks/CU (same occupancy class as k_hid).
__global__ __launch_bounds__(256) void k_hidpi(const float* __restrict__ feat,
    const float* __restrict__ d0W, const float* __restrict__ d0b,
    const float* __restrict__ d1W, const float* __restrict__ d1b,
    const float* __restrict__ gum,
    float* __restrict__ d0a, float* __restrict__ d1a)
{
  __shared__ __align__(16) float fT[446*36];   // fT[ch*36 + r]
  __shared__ __align__(16) float hidT[32*104]; // hid tile, stride 104
  size_t r0 = (size_t)blockIdx.x * 32;
  int tid = threadIdx.x;
  for (int r = 0; r < 32; ++r){
    fT[tid*36 + r] = feat[(r0 + r)*FCH + tid];
    if (tid < 190) fT[(tid + 256)*36 + r] = feat[(r0 + r)*FCH + tid + 256];
  }
  __syncthreads();
  int cs = tid & 31, rq = tid >> 5;            // 32 c-slots (4 cols each), 8 row-quads
  if (cs < 25){
    float4 accv[4];
    #pragma unroll
    for (int jc = 0; jc < 4; ++jc) accv[jc] = make_float4(0.f,0.f,0.f,0.f);
    for (int k = 0; k < 446; ++k){
      float4 xv = *(const float4*)&fT[k*36 + 4*rq];
      float4 wv = *(const float4*)&d0W[k*100 + 4*cs];
      accv[0].x = fmaf(xv.x, wv.x, accv[0].x); accv[0].y = fmaf(xv.y, wv.x, accv[0].y);
      accv[0].z = fmaf(xv.z, wv.x, accv[0].z); accv[0].w = fmaf(xv.w, wv.x, accv[0].w);
      accv[1].x = fmaf(xv.x, wv.y, accv[1].x); accv[1].y = fmaf(xv.y, wv.y, accv[1].y);
      accv[1].z = fmaf(xv.z, wv.y, accv[1].z); accv[1].w = fmaf(xv.w, wv.y, accv[1].w);
      accv[2].x = fmaf(xv.x, wv.z, accv[2].x); accv[2].y = fmaf(xv.y, wv.z, accv[2].y);
      accv[2].z = fmaf(xv.z, wv.z, accv[2].z); accv[2].w = fmaf(xv.w, wv.z, accv[2].w);
      accv[3].x = fmaf(xv.x, wv.w, accv[3].x); accv[3].y = fmaf(xv.y, wv.w, accv[3].y);
      accv[3].z = fmaf(xv.z, wv.w, accv[3].z); accv[3].w = fmaf(xv.w, wv.w, accv[3].w);
    }
    #pragma unroll
    for (int i = 0; i < 4; ++i){
      int rl = 4*rq + i;
      float4 o;
      float vi[4] = { i==0?accv[0].x:(i==1?accv[0].y:(i==2?accv[0].z:accv[0].w)),
                      i==0?accv[1].x:(i==1?accv[1].y:(i==2?accv[1].z:accv[1].w)),
                      i==0?accv[2].x:(i==1?accv[2].y:(i==2?accv[2].z:accv[2].w)),
                      i==0?accv[3].x:(i==1?accv[3].y:(i==2?accv[3].z:accv[3].w)) };
      o.x = fmaxf(vi[0] + d0b[4*cs+0], 0.0f);
      o.y = fmaxf(vi[1] + d0b[4*cs+1], 0.0f);
      o.z = fmaxf(vi[2] + d0b[4*cs+2], 0.0f);
      o.w = fmaxf(vi[3] + d0b[4*cs+3], 0.0f);
      *(float4*)&hidT[rl*104 + 4*cs] = o;
    }
  }
  __syncthreads();
  if (tid < 64){
    int r = tid >> 1, pp = tid & 1;
    float s = d1b[pp];
    for (int m2 = 0; m2 < 100; ++m2) s = fmaf(hidT[r*104 + m2], d1W[m2*2 + pp], s);
    size_t row = r0 + r;
    float a = (s + gum[row*2 + pp]) / 1e-5f;
    float other = __shfl_xor(a, 1);
    float mx = fmaxf(a, other);
    float ea = expf(a - mx), eb = expf(other - mx);
    float d = ea / (ea + eb);
    if (pp == 0) d0a[row] = d; else d1a[row] = d;
  }
}

// ---------------- xzG[((g*T + t)*2048 + col)*4 + b'] = x[b][t] @ cell_Wx + cell_b ----------
__global__ __launch_bounds__(256) void k_xz(const float* __restrict__ x,
    const float* __restrict__ Wx, const float* __restrict__ cb, float* __restrict__ xzG){
  __shared__ __align__(16) float xT[256*36];   // xT[e*36 + b]
  int t  = blockIdx.x & 511;
  int c0 = (blockIdx.x >> 9) * 128;
  int tid = threadIdx.x;
  for (int b = 0; b < 32; ++b){
    xT[tid*36 + b] = x[(b*Tz + t)*Ez + tid];
  }
  __syncthreads();
  int cs = tid & 31, rq = tid >> 5;            // 32 col-slots (4 cols), 8 batch-quads (=groups)
  float4 accv[4];
  #pragma unroll
  for (int jc = 0; jc < 4; ++jc) accv[jc] = make_float4(0.f,0.f,0.f,0.f);
  float4 wv = *(const float4*)&Wx[c0 + 4*cs];  // e = 0 prefetch
  for (int e = 0; e < 256; ++e){
    float4 wc = wv;
    if (e != 255) wv = *(const float4*)&Wx[(e+1)*2048 + c0 + 4*cs];
    float4 xv = *(const float4*)&xT[e*36 + 4*rq];
    accv[0].x = fmaf(xv.x, wc.x, accv[0].x); accv[0].y = fmaf(xv.y, wc.x, accv[0].y);
    accv[0].z = fmaf(xv.z, wc.x, accv[0].z); accv[0].w = fmaf(xv.w, wc.x, accv[0].w);
    accv[1].x = fmaf(xv.x, wc.y, accv[1].x); accv[1].y = fmaf(xv.y, wc.y, accv[1].y);
    accv[1].z = fmaf(xv.z, wc.y, accv[1].z); accv[1].w = fmaf(xv.w, wc.y, accv[1].w);
    accv[2].x = fmaf(xv.x, wc.z, accv[2].x); accv[2].y = fmaf(xv.y, wc.z, accv[2].y);
    accv[2].z = fmaf(xv.z, wc.z, accv[2].z); accv[2].w = fmaf(xv.w, wc.z, accv[2].w);
    accv[3].x = fmaf(xv.x, wc.w, accv[3].x); accv[3].y = fmaf(xv.y, wc.w, accv[3].y);
    accv[3].z = fmaf(xv.z, wc.w, accv[3].z); accv[3].w = fmaf(xv.w, wc.w, accv[3].w);
  }
  #pragma unroll
  for (int jc = 0; jc < 4; ++jc){
    int col = c0 + 4*cs + jc;
    float bv = cb[col];
    float4 o = accv[jc];
    o.x += bv; o.y += bv; o.z += bv; o.w += bv;
    *(float4*)&xzG[(((size_t)rq*Tz + t)*2048 + col)*4] = o;
  }
}

// ---------------- persistent scan kernel: round-0 lockstep + h_reg (verified 1705us) ----
__global__ __launch_bounds__(512, 2) void k_scan(
    const float* __restrict__ Wh, const float* __restrict__ xzG,
    const float* __restrict__ d0a, const float* __restrict__ d1a,
    float* __restrict__ hG,              // [8 groups][2 bufs][4*512]
    unsigned int* __restrict__ tags,     // [8][32]
    float* __restrict__ out)
{
  __shared__ __align__(16) float hL[4*520];    // swizzled h, row stride 520
  __shared__ __align__(16) float part[8*260];  // 8 kgroups x 64 cols x 4 b, stride 260
  __shared__ float zL[256];
  __shared__ float hcandL[64];
  __shared__ float dv0L[2048];                 // [t*4 + bb], staged once
  __shared__ float dv1L[2048];

  int tid = threadIdx.x;
  int g = blockIdx.x & 7;
  int m = blockIdx.x >> 3;
  int w = tid >> 6;                      // wave 0..7
  int lane = tid & 63;                   // = kseg

  float wreg[8][8];
  {
    int colbase = ((w >> 1) << 9) + (m << 4) + ((w & 1) << 3);
    #pragma unroll
    for (int j = 0; j < 8; ++j){
      const float4* wp = (const float4*)(Wh + (size_t)(lane*8 + j)*2048 + colbase);
      float4 a = wp[0], bq = wp[1];
      wreg[0][j]=a.x;  wreg[1][j]=a.y;  wreg[2][j]=a.z;  wreg[3][j]=a.w;
      wreg[4][j]=bq.x; wreg[5][j]=bq.y; wreg[6][j]=bq.z; wreg[7][j]=bq.w;
    }
  }
  for (int i = tid; i < 2048; i += 512){
    int tt = i >> 2, bb = i & 3;
    dv0L[i] = d0a[tt*32 + (g << 2) + bb];
    dv1L[i] = d1a[tt*32 + (g << 2) + bb];
  }

  int q0 = 2*lane;
  int sw = (q0 >> 3) & 3;
  int p0 = ((q0  ) ^ sw) << 2;
  int p1 = ((q0+1) ^ sw) << 2;

  int stb = tid >> 7, stq = tid & 127;
  int stp = (stq ^ ((stq >> 3) & 3)) << 2;
  const int hrow = 520;
  const unsigned int* mytag = tags + (g << 5) + (stq >> 2);

  int rcg = tid >> 2, rb = tid & 3;
  int rcol = ((rcg >> 4) << 9) + (m << 4) + (rcg & 15);
  size_t xzbase = ((size_t)g*Tz)*8192 + (size_t)rcol*4 + rb;

  float* hg0 = hG + (size_t)(g*2 + 0) * (4*512);
  float* hg1 = hG + (size_t)(g*2 + 1) * (4*512);

  float c_reg = 0.0f;                    // cell state (tid<64: bb=tid&3, jl=tid>>2)
  float h_reg = 0.0f;                    // own h state (tid<64) — hold == prev hnew

  for (int t = 0; t < Tz; ++t){
    const float* hcur = (t & 1) ? hg1 : hg0;
    float*       hnxt = (t & 1) ? hg0 : hg1;

    // ---- stage group h (gen t): poll own producer's tag, then load its quad ----
    if (t == 0){
      *(float4*)&hL[stb*hrow + stp] = make_float4(0.f,0.f,0.f,0.f);
    } else {
      while (__hip_atomic_load(mytag, __ATOMIC_RELAXED, __HIP_MEMORY_SCOPE_AGENT)
             < (unsigned)t) { }
      const float* src = hcur + stb*512 + stq*4;
      float4 v;
      v.x = __hip_atomic_load(src+0, __ATOMIC_RELAXED, __HIP_MEMORY_SCOPE_AGENT);
      v.y = __hip_atomic_load(src+1, __ATOMIC_RELAXED, __HIP_MEMORY_SCOPE_AGENT);
      v.z = __hip_atomic_load(src+2, __ATOMIC_RELAXED, __HIP_MEMORY_SCOPE_AGENT);
      v.w = __hip_atomic_load(src+3, __ATOMIC_RELAXED, __HIP_MEMORY_SCOPE_AGENT);
      *(float4*)&hL[stb*hrow + stp] = v;
    }
    float xzv = 0.0f;
    if (tid < 256) xzv = xzG[xzbase + (size_t)t*8192];
    __syncthreads();

    // ---- matvec: acc[8 cols][4 b] over k in [lane*8, lane*8+8) ----
    float acc[8][4];
    #pragma unroll
    for (int ci = 0; ci < 8; ++ci)
      #pragma unroll
      for (int b = 0; b < 4; ++b) acc[ci][b] = 0.0f;
    #pragma unroll
    for (int b = 0; b < 4; ++b){
      const float* hr = &hL[b*hrow];
      float4 h0 = *(const float4*)(hr + p0);
      float4 h1 = *(const float4*)(hr + p1);
      float hv[8] = {h0.x,h0.y,h0.z,h0.w,h1.x,h1.y,h1.z,h1.w};
      #pragma unroll
      for (int j = 0; j < 8; ++j){
        #pragma unroll
        for (int ci = 0; ci < 8; ++ci)
          acc[ci][b] = fmaf(wreg[ci][j], hv[j], acc[ci][b]);
      }
    }

    // ---- value-splitting butterfly: 64 partials/z -> 8, in registers ----
    float v16[16];
    {
      bool hi = (lane & 1);
      #pragma unroll
      for (int i = 0; i < 16; ++i){
        int ci = i >> 2, b = i & 3;
        float keep = hi ? acc[4+ci][b] : acc[ci][b];
        float send = hi ? acc[ci][b]   : acc[4+ci][b];
        v16[i] = keep + __shfl_xor(send, 1);
      }
    }
    float v8[8];
    {
      bool hi = (lane & 2);
      #pragma unroll
      for (int i = 0; i < 8; ++i){
        float keep = hi ? v16[8+i] : v16[i];
        float send = hi ? v16[i]   : v16[8+i];
        v8[i] = keep + __shfl_xor(send, 2);
      }
    }
    float v4[4];
    {
      bool hi = (lane & 4);
      #pragma unroll
      for (int b = 0; b < 4; ++b){
        float keep = hi ? v8[4+b] : v8[b];
        float send = hi ? v8[b]   : v8[4+b];
        v4[b] = keep + __shfl_xor(send, 4);
      }
    }
    {
      int e = ((lane & 1) << 2) | (lane & 2) | ((lane >> 2) & 1);
      float* pw = &part[(lane >> 3)*260 + ((8*w + e) << 2)];
      *(float4*)pw = make_float4(v4[0], v4[1], v4[2], v4[3]);
    }
    __syncthreads();

    // ---- final reduce: 8 partials per z ----
    if (tid < 256){
      float s0 = part[0*260 + tid] + part[1*260 + tid];
      float s1 = part[2*260 + tid] + part[3*260 + tid];
      float s2 = part[4*260 + tid] + part[5*260 + tid];
      float s3 = part[6*260 + tid] + part[7*260 + tid];
      zL[tid] = (s0+s1)+(s2+s3) + xzv;
    }
    __syncthreads();

    // ---- gates + publish (wave 0) ----
    if (tid < 64){
      int jl = tid >> 2, bb = tid & 3;
      float zi = zL[      (jl << 2) + bb];
      float zf = zL[ 64 + (jl << 2) + bb];
      float zg = zL[128 + (jl << 2) + bb];
      float zo = zL[192 + (jl << 2) + bb];
      float dv0 = dv0L[(t << 2) + bb];
      float dv1 = dv1L[(t << 2) + bb];
      int hk = (m << 4) + jl;
      float ccand = sigf(zf)*c_reg + sigf(zi)*tanhfast(zg);
      float hcand = sigf(zo)*tanhfast(ccand);
      c_reg = dv0*ccand + dv1*c_reg;
      float hnew = dv0*hcand + dv1*h_reg;
      h_reg = hnew;
      hcandL[(bb << 4) + jl] = hcand;
      __hip_atomic_store(hnxt + bb*512 + hk, hnew,
                         __ATOMIC_RELAXED, __HIP_MEMORY_SCOPE_AGENT);
    }
    __syncthreads();                     // drains wave 0's publish (vmcnt) in all waves

    // tag publish (tid0) + out store (wave 1) — both off the next-staging path
    if (tid == 0){
      __hip_atomic_store(tags + (g << 5) + m, (unsigned)(t+1),
                         __ATOMIC_RELAXED, __HIP_MEMORY_SCOPE_AGENT);
    }
    if (tid >= 64 && tid < 80){
      int idx = tid - 64; int bb = idx >> 2, q = idx & 3;
      float4 v = *(const float4*)&hcandL[(bb << 4) + 4*q];
      *(float4*)(out + (size_t)((g << 2) + bb)*(Tz*Hz) + (size_t)t*Hz + (m << 4) + 4*q) = v;
    }
  }
}

extern "C" void kernel_launch(void* const* d_in, const int* in_sizes, int n_in,
                              void* d_out, int out_size, void* d_ws, size_t ws_size,
                              hipStream_t stream)
{
  const float* x       = (const float*)d_in[0];
  const float* conv1_w = (const float*)d_in[1];
  const float* conv1_b = (const float*)d_in[2];
  const float* conv2_w = (const float*)d_in[3];
  const float* conv2_b = (const float*)d_in[4];
  const float* conv3_w = (const float*)d_in[5];
  const float* conv3_b = (const float*)d_in[6];
  const float* rev_Wx  = (const float*)d_in[7];
  const float* rev_Wh  = (const float*)d_in[8];
  const float* rev_b   = (const float*)d_in[9];
  const float* d0_W    = (const float*)d_in[10];
  const float* d0_b    = (const float*)d_in[11];
  const float* d1_W    = (const float*)d_in[12];
  const float* d1_b    = (const float*)d_in[13];
  const float* cell_Wx = (const float*)d_in[14];
  const float* cell_Wh = (const float*)d_in[15];
  const float* cell_b  = (const float*)d_in[16];
  const float* gumbel  = (const float*)d_in[17];
  float* out = (float*)d_out;

  char* ws = (char*)d_ws;
  size_t off = 0;
  float* xzG  = (float*)(ws + off); off += (size_t)Tz*2048*Bz*4;       // 134 MB
  float* feat = (float*)(ws + off); off += (size_t)Tz*Bz*FCH*4;        // 29 MB
  float* rxw  = (float*)(ws + off); off += (size_t)Tz*Bz*40*4;         // 2.6 MB
  float* d0a  = (float*)(ws + off); off += (size_t)Tz*Bz*4;
  float* d1a  = (float*)(ws + off); off += (size_t)Tz*Bz*4;
  float* hG   = (float*)(ws + off); off += (size_t)8*2*4*512*4;        // 128 KB
  unsigned int* tags = (unsigned int*)(ws + off); off += 8*32*4;       // 1 KB

  // zero-init: feat row T-1 (ff tail zeros; conv writes its x-part), tags
  hipMemsetAsync(feat + (size_t)(Tz-1)*Bz*FCH, 0, Bz*FCH*4, stream);
  hipMemsetAsync(tags, 0, 8*32*4, stream);

  k_conv<<<512, 256, 0, stream>>>(x, conv1_w, conv1_b, conv2_w, conv2_b,
                                  conv3_w, conv3_b, rev_Wx, feat, rxw);
  k_rev<<<32, 64, 0, stream>>>(rxw, rev_Wh, rev_b, feat);
  k_hidpi<<<512, 256, 0, stream>>>(feat, d0_W, d0_b, d1_W, d1_b, gumbel, d0a, d1a);
  k_xz<<<8192, 256, 0, stream>>>(x, cell_Wx, cell_b, xzG);

  k_scan<<<256, 512, 0, stream>>>(cell_Wh, xzG, d0a, d1a, hG, tags, out);
}